// Round 3
// baseline (212.850 us; speedup 1.0000x reference)
//
#include <hip/hip_runtime.h>

typedef __bf16 bf16;
typedef __bf16 bf16x8 __attribute__((ext_vector_type(8)));
typedef float  f32x4  __attribute__((ext_vector_type(4)));

#define T_SEQ  2048
#define NHEAD  16
#define DHEAD  64
#define DMODEL 1024
#define MTOT   4096  // B*T

static __device__ __forceinline__ f32x4 mfma16(bf16x8 a, bf16x8 b, f32x4 c) {
    return __builtin_amdgcn_mfma_f32_16x16x32_bf16(a, b, c, 0, 0, 0);
}

// ---------------------------------------------------------------------------
// fp32 -> bf16 elementwise convert (8 elems/thread).
// ---------------------------------------------------------------------------
__global__ __launch_bounds__(256) void convert_f32_bf16(
    const float* __restrict__ in, bf16* __restrict__ out)
{
    const int i = blockIdx.x * 256 + threadIdx.x;   // index over 8-elem groups
    const float4 a = ((const float4*)in)[i * 2];
    const float4 b = ((const float4*)in)[i * 2 + 1];
    bf16x8 v;
    v[0] = (bf16)a.x; v[1] = (bf16)a.y; v[2] = (bf16)a.z; v[3] = (bf16)a.w;
    v[4] = (bf16)b.x; v[5] = (bf16)b.y; v[6] = (bf16)b.z; v[7] = (bf16)b.w;
    ((bf16x8*)out)[i] = v;
}

// ---------------------------------------------------------------------------
// 64x64-tiled transpose, fp32 in -> bf16 out: out[c][r] = (bf16)in[r][c].
// Batched over z (ibs/obs = element batch strides).
// ---------------------------------------------------------------------------
__global__ __launch_bounds__(256) void transpose_f32_bf16(
    const float* __restrict__ in, bf16* __restrict__ out,
    int R, int Cc, long ibs, long obs)
{
    __shared__ float t[64][68];
    const int r0 = blockIdx.x * 64, c0 = blockIdx.y * 64;
    const long ib = ibs * (long)blockIdx.z, ob = obs * (long)blockIdx.z;
    const int tid = threadIdx.x;

#pragma unroll
    for (int i = 0; i < 4; ++i) {                   // load 64x64 fp32 tile
        int idx = i * 256 + tid;
        int row = idx >> 4, cb = (idx & 15) * 4;
        float4 v = *(const float4*)&in[ib + (long)(r0 + row) * Cc + c0 + cb];
        t[row][cb + 0] = v.x; t[row][cb + 1] = v.y;
        t[row][cb + 2] = v.z; t[row][cb + 3] = v.w;
    }
    __syncthreads();
#pragma unroll
    for (int i = 0; i < 2; ++i) {                   // store 64x64 bf16 transposed
        int idx = i * 256 + tid;
        int row = idx >> 3, cb = (idx & 7) * 8;     // row = out-row (col of in)
        bf16x8 v;
#pragma unroll
        for (int j = 0; j < 8; ++j) v[j] = (bf16)t[cb + j][row];
        *(bf16x8*)&out[ob + (long)(c0 + row) * R + r0 + cb] = v;
    }
}

// ---------------------------------------------------------------------------
// QKV projection: q/k/v[b,h,t,d] = x[b,t,:] @ W[h,:,d] + bias.
// x: [4096,1024] bf16.  wt: [3*H][64][1024] pre-transposed bf16 weights.
// Writes q,k as [b,h,t,d]; v transposed as [b,h,d,t].
// ---------------------------------------------------------------------------
__global__ __launch_bounds__(256) void qkv_gemm(
    const bf16* __restrict__ x, const bf16* __restrict__ wt,
    const float* __restrict__ bq, const float* __restrict__ bk,
    const float* __restrict__ bv,
    bf16* __restrict__ qws, bf16* __restrict__ kws, bf16* __restrict__ vtws)
{
    __shared__ __align__(16) bf16 xs[128][72];
    __shared__ __align__(16) bf16 wsh[3][64][72];

    const int m0 = blockIdx.x * 128;
    const int h  = blockIdx.y;
    const int tid = threadIdx.x, wid = tid >> 6, lane = tid & 63;
    const int lr = lane & 15, lg = lane >> 4;

    const bf16* wbase[3];
#pragma unroll
    for (int w = 0; w < 3; ++w)
        wbase[w] = wt + ((size_t)(w * NHEAD + h)) * DHEAD * DMODEL;

    f32x4 acc[3][2][4];
#pragma unroll
    for (int w = 0; w < 3; ++w)
#pragma unroll
        for (int mi = 0; mi < 2; ++mi)
#pragma unroll
            for (int nt = 0; nt < 4; ++nt) acc[w][mi][nt] = (f32x4)0.0f;

    for (int kt = 0; kt < 16; ++kt) {
        const int kofs = kt * 64;
        __syncthreads();
#pragma unroll
        for (int i = 0; i < 4; ++i) {            // x tile: 128x64
            int idx = i * 256 + tid;
            int row = idx >> 3, cb = (idx & 7) * 8;
            *(bf16x8*)&xs[row][cb] =
                *(const bf16x8*)&x[(size_t)(m0 + row) * DMODEL + kofs + cb];
        }
#pragma unroll
        for (int w = 0; w < 3; ++w)
#pragma unroll
            for (int i = 0; i < 2; ++i) {        // wt tiles: 64x64 each
                int idx = i * 256 + tid;
                int row = idx >> 3, cb = (idx & 7) * 8;
                *(bf16x8*)&wsh[w][row][cb] =
                    *(const bf16x8*)&wbase[w][(size_t)row * DMODEL + kofs + cb];
            }
        __syncthreads();

        bf16x8 af[2][2];
#pragma unroll
        for (int mi = 0; mi < 2; ++mi)
#pragma unroll
            for (int ks = 0; ks < 2; ++ks)
                af[mi][ks] = *(const bf16x8*)&xs[wid * 32 + mi * 16 + lr][ks * 32 + lg * 8];

#pragma unroll
        for (int w = 0; w < 3; ++w)
#pragma unroll
            for (int nt = 0; nt < 4; ++nt)
#pragma unroll
                for (int ks = 0; ks < 2; ++ks) {
                    bf16x8 bfr = *(const bf16x8*)&wsh[w][nt * 16 + lr][ks * 32 + lg * 8];
#pragma unroll
                    for (int mi = 0; mi < 2; ++mi)
                        acc[w][mi][nt] = mfma16(af[mi][ks], bfr, acc[w][mi][nt]);
                }
    }

    const float* bias[3] = { bq + h * DHEAD, bk + h * DHEAD, bv + h * DHEAD };
#pragma unroll
    for (int w = 0; w < 3; ++w)
#pragma unroll
        for (int nt = 0; nt < 4; ++nt) {
            int d = nt * 16 + lr;
            float bs = bias[w][d];
#pragma unroll
            for (int mi = 0; mi < 2; ++mi)
#pragma unroll
                for (int j = 0; j < 4; ++j) {
                    int mrow = m0 + wid * 32 + mi * 16 + lg * 4 + j;
                    int b = mrow >> 11, t = mrow & 2047;
                    float val = acc[w][mi][nt][j] + bs;
                    size_t bh = (size_t)b * NHEAD + h;
                    if (w == 0)
                        qws[(bh * T_SEQ + t) * DHEAD + d] = (bf16)val;
                    else if (w == 1)
                        kws[(bh * T_SEQ + t) * DHEAD + d] = (bf16)val;
                    else
                        vtws[(bh * DHEAD + d) * T_SEQ + t] = (bf16)val;
                }
        }
}

// ---------------------------------------------------------------------------
// Fused flash attention (non-causal, scale = 1/sqrt(DMODEL) = 1/32).
// Grid: (T/64 q-tiles, B*H). Block: 4 waves, each owns 16 q-rows.
// Output written as [b, t, h*64+d] (head-concat layout for the out-proj).
// ---------------------------------------------------------------------------
__global__ __launch_bounds__(256) void attn_fused(
    const bf16* __restrict__ qws, const bf16* __restrict__ kws,
    const bf16* __restrict__ vtws, bf16* __restrict__ aws)
{
    __shared__ __align__(16) bf16 kls[64][72];
    __shared__ __align__(16) bf16 vls[64][72];
    __shared__ __align__(16) bf16 pls[64][72];

    const int qt = blockIdx.x;
    const int bh = blockIdx.y;
    const int b = bh >> 4, h = bh & 15;
    const bf16* Q  = qws  + (size_t)bh * T_SEQ * DHEAD;
    const bf16* K  = kws  + (size_t)bh * T_SEQ * DHEAD;
    const bf16* Vt = vtws + (size_t)bh * DHEAD * T_SEQ;

    const int tid = threadIdx.x, wid = tid >> 6, lane = tid & 63;
    const int lr = lane & 15, lg = lane >> 4;
    const int q0 = qt * 64 + wid * 16;

    bf16x8 qf[2];
#pragma unroll
    for (int ks = 0; ks < 2; ++ks)
        qf[ks] = *(const bf16x8*)&Q[(size_t)(q0 + lr) * DHEAD + ks * 32 + lg * 8];

    f32x4 o[4];
#pragma unroll
    for (int nt = 0; nt < 4; ++nt) o[nt] = (f32x4)0.0f;
    float mrun[4] = { -1e30f, -1e30f, -1e30f, -1e30f };
    float lrun[4] = { 0.f, 0.f, 0.f, 0.f };

    for (int kv0 = 0; kv0 < T_SEQ; kv0 += 64) {
        __syncthreads();
#pragma unroll
        for (int i = 0; i < 2; ++i) {
            int idx = i * 256 + tid;
            int row = idx >> 3, cb = (idx & 7) * 8;
            *(bf16x8*)&kls[row][cb] =
                *(const bf16x8*)&K[(size_t)(kv0 + row) * DHEAD + cb];
            *(bf16x8*)&vls[row][cb] =
                *(const bf16x8*)&Vt[(size_t)row * T_SEQ + kv0 + cb];
        }
        __syncthreads();

        // S = Q K^T (scaled by 1/32)
        f32x4 s[4];
#pragma unroll
        for (int nt = 0; nt < 4; ++nt) {
            bf16x8 k0 = *(const bf16x8*)&kls[nt * 16 + lr][0 + lg * 8];
            bf16x8 k1 = *(const bf16x8*)&kls[nt * 16 + lr][32 + lg * 8];
            s[nt] = mfma16(qf[0], k0, (f32x4)0.0f);
            s[nt] = mfma16(qf[1], k1, s[nt]);
            s[nt] *= 0.03125f;
        }

        // online softmax (row = 4*lg + j within the wave's 16 q-rows)
#pragma unroll
        for (int j = 0; j < 4; ++j) {
            float v = fmaxf(fmaxf(s[0][j], s[1][j]), fmaxf(s[2][j], s[3][j]));
            v = fmaxf(v, __shfl_xor(v, 1));
            v = fmaxf(v, __shfl_xor(v, 2));
            v = fmaxf(v, __shfl_xor(v, 4));
            v = fmaxf(v, __shfl_xor(v, 8));
            float mnew = fmaxf(mrun[j], v);
            float alpha = __expf(mrun[j] - mnew);
            mrun[j] = mnew;
            float rs = 0.f;
#pragma unroll
            for (int nt = 0; nt < 4; ++nt) {
                float p = __expf(s[nt][j] - mnew);
                rs += p;
                pls[wid * 16 + lg * 4 + j][nt * 16 + lr] = (bf16)p;
            }
            rs += __shfl_xor(rs, 1);
            rs += __shfl_xor(rs, 2);
            rs += __shfl_xor(rs, 4);
            rs += __shfl_xor(rs, 8);
            lrun[j] = lrun[j] * alpha + rs;
#pragma unroll
            for (int nt = 0; nt < 4; ++nt) o[nt][j] *= alpha;
        }
        __syncthreads();

        // O += P V
#pragma unroll
        for (int ks = 0; ks < 2; ++ks) {
            bf16x8 pf = *(const bf16x8*)&pls[wid * 16 + lr][ks * 32 + lg * 8];
#pragma unroll
            for (int nt = 0; nt < 4; ++nt) {
                bf16x8 vf = *(const bf16x8*)&vls[nt * 16 + lr][ks * 32 + lg * 8];
                o[nt] = mfma16(pf, vf, o[nt]);
            }
        }
    }

    float inv[4];
#pragma unroll
    for (int j = 0; j < 4; ++j) inv[j] = 1.0f / lrun[j];
    const size_t obase = ((size_t)b * T_SEQ) * DMODEL + (size_t)h * DHEAD;
#pragma unroll
    for (int nt = 0; nt < 4; ++nt) {
        int d = nt * 16 + lr;
#pragma unroll
        for (int j = 0; j < 4; ++j) {
            int t = q0 + lg * 4 + j;
            aws[obase + (size_t)t * DMODEL + d] = (bf16)(o[nt][j] * inv[j]);
        }
    }
}

// ---------------------------------------------------------------------------
// Output projection: out = attn [4096,1024] @ Wo [1024,1024] + bo.
// d_out is FP32 (reference output dtype).
// ---------------------------------------------------------------------------
__global__ __launch_bounds__(256) void out_gemm(
    const bf16* __restrict__ a, const bf16* __restrict__ wot,
    const float* __restrict__ bo, float* __restrict__ out)
{
    __shared__ __align__(16) bf16 as[128][72];
    __shared__ __align__(16) bf16 wsh[64][72];

    const int m0 = blockIdx.x * 128, n0 = blockIdx.y * 64;
    const int tid = threadIdx.x, wid = tid >> 6, lane = tid & 63;
    const int lr = lane & 15, lg = lane >> 4;

    f32x4 acc[2][4];
#pragma unroll
    for (int mi = 0; mi < 2; ++mi)
#pragma unroll
        for (int nt = 0; nt < 4; ++nt) acc[mi][nt] = (f32x4)0.0f;

    for (int kt = 0; kt < 16; ++kt) {
        const int kofs = kt * 64;
        __syncthreads();
#pragma unroll
        for (int i = 0; i < 4; ++i) {
            int idx = i * 256 + tid;
            int row = idx >> 3, cb = (idx & 7) * 8;
            *(bf16x8*)&as[row][cb] =
                *(const bf16x8*)&a[(size_t)(m0 + row) * DMODEL + kofs + cb];
        }
#pragma unroll
        for (int i = 0; i < 2; ++i) {
            int idx = i * 256 + tid;
            int row = idx >> 3, cb = (idx & 7) * 8;
            *(bf16x8*)&wsh[row][cb] =
                *(const bf16x8*)&wot[(size_t)(n0 + row) * DMODEL + kofs + cb];
        }
        __syncthreads();

        bf16x8 af[2][2];
#pragma unroll
        for (int mi = 0; mi < 2; ++mi)
#pragma unroll
            for (int ks = 0; ks < 2; ++ks)
                af[mi][ks] = *(const bf16x8*)&as[wid * 32 + mi * 16 + lr][ks * 32 + lg * 8];

#pragma unroll
        for (int nt = 0; nt < 4; ++nt)
#pragma unroll
            for (int ks = 0; ks < 2; ++ks) {
                bf16x8 bfr = *(const bf16x8*)&wsh[nt * 16 + lr][ks * 32 + lg * 8];
#pragma unroll
                for (int mi = 0; mi < 2; ++mi)
                    acc[mi][nt] = mfma16(af[mi][ks], bfr, acc[mi][nt]);
            }
    }

#pragma unroll
    for (int nt = 0; nt < 4; ++nt) {
        int n = n0 + nt * 16 + lr;
        float bs = bo[n];
#pragma unroll
        for (int mi = 0; mi < 2; ++mi)
#pragma unroll
            for (int j = 0; j < 4; ++j) {
                int m = m0 + wid * 32 + mi * 16 + lg * 4 + j;
                out[(size_t)m * DMODEL + n] = acc[mi][nt][j] + bs;
            }
    }
}

// ---------------------------------------------------------------------------
extern "C" void kernel_launch(void* const* d_in, const int* in_sizes, int n_in,
                              void* d_out, int out_size, void* d_ws, size_t ws_size,
                              hipStream_t stream)
{
    const float* x  = (const float*)d_in[0];
    const float* Wq = (const float*)d_in[1];
    const float* Wk = (const float*)d_in[2];
    const float* Wv = (const float*)d_in[3];
    const float* bq = (const float*)d_in[4];
    const float* bk = (const float*)d_in[5];
    const float* bv = (const float*)d_in[6];
    const float* Wo = (const float*)d_in[7];
    const float* bo = (const float*)d_in[8];
    float* out = (float*)d_out;

    const size_t M1 = (size_t)1024 * 1024;
    bf16* ws   = (bf16*)d_ws;
    bf16* xbf  = ws;                 // 4M elems [4096][1024]; reused as aws later
    bf16* qws  = ws + 4 * M1;        // 4M  [b,h,t,d]
    bf16* kws  = qws + 4 * M1;       // 4M  [b,h,t,d]
    bf16* vtws = kws + 4 * M1;       // 4M  [b,h,d,t]
    bf16* wt   = vtws + 4 * M1;      // 3M  [3*h][d][c]
    bf16* wot  = wt + 3 * M1;        // 1M  [n][k]
    bf16* aws  = xbf;                // alias: x dead after qkv_gemm
    // total: 20M bf16 = 40 MB

    dim3 tb(256);
    convert_f32_bf16<<<dim3(MTOT * DMODEL / (256 * 8)), tb, 0, stream>>>(x, xbf);
    transpose_f32_bf16<<<dim3(16, 1, 16), tb, 0, stream>>>(Wq, wt + 0 * M1, 1024, 64, 65536, 65536);
    transpose_f32_bf16<<<dim3(16, 1, 16), tb, 0, stream>>>(Wk, wt + 1 * M1, 1024, 64, 65536, 65536);
    transpose_f32_bf16<<<dim3(16, 1, 16), tb, 0, stream>>>(Wv, wt + 2 * M1, 1024, 64, 65536, 65536);
    transpose_f32_bf16<<<dim3(16, 16, 1), tb, 0, stream>>>(Wo, wot, 1024, 1024, 0, 0);

    qkv_gemm<<<dim3(MTOT / 128, NHEAD), tb, 0, stream>>>(xbf, wt, bq, bk, bv, qws, kws, vtws);
    attn_fused<<<dim3(T_SEQ / 64, 2 * NHEAD), tb, 0, stream>>>(qws, kws, vtws, aws);
    out_gemm<<<dim3(MTOT / 128, DMODEL / 64), tb, 0, stream>>>(aws, wot, bo, out);
}

// Round 4
// 178.961 us; speedup vs baseline: 1.1894x; 1.1894x over previous
//
#include <hip/hip_runtime.h>

typedef __bf16 bf16;
typedef __bf16 bf16x8 __attribute__((ext_vector_type(8)));
typedef float  f32x4  __attribute__((ext_vector_type(4)));

#define T_SEQ  2048
#define NHEAD  16
#define DHEAD  64
#define DMODEL 1024
#define MTOT   4096  // B*T

static __device__ __forceinline__ f32x4 mfma16(bf16x8 a, bf16x8 b, f32x4 c) {
    return __builtin_amdgcn_mfma_f32_16x16x32_bf16(a, b, c, 0, 0, 0);
}

// ---------------------------------------------------------------------------
// fp32 -> bf16 elementwise convert (8 elems/thread).
// ---------------------------------------------------------------------------
__global__ __launch_bounds__(256) void convert_f32_bf16(
    const float* __restrict__ in, bf16* __restrict__ out)
{
    const int i = blockIdx.x * 256 + threadIdx.x;   // index over 8-elem groups
    const float4 a = ((const float4*)in)[i * 2];
    const float4 b = ((const float4*)in)[i * 2 + 1];
    bf16x8 v;
    v[0] = (bf16)a.x; v[1] = (bf16)a.y; v[2] = (bf16)a.z; v[3] = (bf16)a.w;
    v[4] = (bf16)b.x; v[5] = (bf16)b.y; v[6] = (bf16)b.z; v[7] = (bf16)b.w;
    ((bf16x8*)out)[i] = v;
}

// ---------------------------------------------------------------------------
// 64x64-tiled transpose, fp32 in -> bf16 out: out[c][r] = (bf16)in[r][c].
// ---------------------------------------------------------------------------
__global__ __launch_bounds__(256) void transpose_f32_bf16(
    const float* __restrict__ in, bf16* __restrict__ out,
    int R, int Cc, long ibs, long obs)
{
    __shared__ float t[64][68];
    const int r0 = blockIdx.x * 64, c0 = blockIdx.y * 64;
    const long ib = ibs * (long)blockIdx.z, ob = obs * (long)blockIdx.z;
    const int tid = threadIdx.x;

#pragma unroll
    for (int i = 0; i < 4; ++i) {                   // load 64x64 fp32 tile
        int idx = i * 256 + tid;
        int row = idx >> 4, cb = (idx & 15) * 4;
        float4 v = *(const float4*)&in[ib + (long)(r0 + row) * Cc + c0 + cb];
        t[row][cb + 0] = v.x; t[row][cb + 1] = v.y;
        t[row][cb + 2] = v.z; t[row][cb + 3] = v.w;
    }
    __syncthreads();
#pragma unroll
    for (int i = 0; i < 2; ++i) {                   // store 64x64 bf16 transposed
        int idx = i * 256 + tid;
        int row = idx >> 3, cb = (idx & 7) * 8;     // row = out-row (col of in)
        bf16x8 v;
#pragma unroll
        for (int j = 0; j < 8; ++j) v[j] = (bf16)t[cb + j][row];
        *(bf16x8*)&out[ob + (long)(c0 + row) * R + r0 + cb] = v;
    }
}

// ---------------------------------------------------------------------------
// QKV projection: q/k/v[b,h,t,d] = x[b,t,:] @ W[h,:,d] + bias.
// ---------------------------------------------------------------------------
__global__ __launch_bounds__(256) void qkv_gemm(
    const bf16* __restrict__ x, const bf16* __restrict__ wt,
    const float* __restrict__ bq, const float* __restrict__ bk,
    const float* __restrict__ bv,
    bf16* __restrict__ qws, bf16* __restrict__ kws, bf16* __restrict__ vtws)
{
    __shared__ __align__(16) bf16 xs[128][72];
    __shared__ __align__(16) bf16 wsh[3][64][72];

    const int m0 = blockIdx.x * 128;
    const int h  = blockIdx.y;
    const int tid = threadIdx.x, wid = tid >> 6, lane = tid & 63;
    const int lr = lane & 15, lg = lane >> 4;

    const bf16* wbase[3];
#pragma unroll
    for (int w = 0; w < 3; ++w)
        wbase[w] = wt + ((size_t)(w * NHEAD + h)) * DHEAD * DMODEL;

    f32x4 acc[3][2][4];
#pragma unroll
    for (int w = 0; w < 3; ++w)
#pragma unroll
        for (int mi = 0; mi < 2; ++mi)
#pragma unroll
            for (int nt = 0; nt < 4; ++nt) acc[w][mi][nt] = (f32x4)0.0f;

    for (int kt = 0; kt < 16; ++kt) {
        const int kofs = kt * 64;
        __syncthreads();
#pragma unroll
        for (int i = 0; i < 4; ++i) {            // x tile: 128x64
            int idx = i * 256 + tid;
            int row = idx >> 3, cb = (idx & 7) * 8;
            *(bf16x8*)&xs[row][cb] =
                *(const bf16x8*)&x[(size_t)(m0 + row) * DMODEL + kofs + cb];
        }
#pragma unroll
        for (int w = 0; w < 3; ++w)
#pragma unroll
            for (int i = 0; i < 2; ++i) {        // wt tiles: 64x64 each
                int idx = i * 256 + tid;
                int row = idx >> 3, cb = (idx & 7) * 8;
                *(bf16x8*)&wsh[w][row][cb] =
                    *(const bf16x8*)&wbase[w][(size_t)row * DMODEL + kofs + cb];
            }
        __syncthreads();

        bf16x8 af[2][2];
#pragma unroll
        for (int mi = 0; mi < 2; ++mi)
#pragma unroll
            for (int ks = 0; ks < 2; ++ks)
                af[mi][ks] = *(const bf16x8*)&xs[wid * 32 + mi * 16 + lr][ks * 32 + lg * 8];

#pragma unroll
        for (int w = 0; w < 3; ++w)
#pragma unroll
            for (int nt = 0; nt < 4; ++nt)
#pragma unroll
                for (int ks = 0; ks < 2; ++ks) {
                    bf16x8 bfr = *(const bf16x8*)&wsh[w][nt * 16 + lr][ks * 32 + lg * 8];
#pragma unroll
                    for (int mi = 0; mi < 2; ++mi)
                        acc[w][mi][nt] = mfma16(af[mi][ks], bfr, acc[w][mi][nt]);
                }
    }

    const float* bias[3] = { bq + h * DHEAD, bk + h * DHEAD, bv + h * DHEAD };
#pragma unroll
    for (int w = 0; w < 3; ++w)
#pragma unroll
        for (int nt = 0; nt < 4; ++nt) {
            int d = nt * 16 + lr;
            float bs = bias[w][d];
#pragma unroll
            for (int mi = 0; mi < 2; ++mi)
#pragma unroll
                for (int j = 0; j < 4; ++j) {
                    int mrow = m0 + wid * 32 + mi * 16 + lg * 4 + j;
                    int b = mrow >> 11, t = mrow & 2047;
                    float val = acc[w][mi][nt][j] + bs;
                    size_t bh = (size_t)b * NHEAD + h;
                    if (w == 0)
                        qws[(bh * T_SEQ + t) * DHEAD + d] = (bf16)val;
                    else if (w == 1)
                        kws[(bh * T_SEQ + t) * DHEAD + d] = (bf16)val;
                    else
                        vtws[(bh * DHEAD + d) * T_SEQ + t] = (bf16)val;
                }
        }
}

// ---------------------------------------------------------------------------
// Fused flash attention, swapped-operand form.
// S^T = mfma(K_frag, Q_frag): each lane holds 16 kv-samples of q-row (lane&15)
//   -> softmax is in-lane + 2 shfl_xor; P stored as packed dwords, wave-private.
// Grid: (T/64 q-tiles, B*H). Block: 4 waves, each owns 16 q-rows.
// ---------------------------------------------------------------------------
__global__ __launch_bounds__(256) void attn_fused(
    const bf16* __restrict__ qws, const bf16* __restrict__ kws,
    const bf16* __restrict__ vtws, bf16* __restrict__ aws)
{
    __shared__ __align__(16) bf16 kls[64][72];
    __shared__ __align__(16) bf16 vls[64][72];
    __shared__ __align__(16) bf16 pls[64][72];

    const int qt = blockIdx.x;
    const int bh = blockIdx.y;
    const int b = bh >> 4, h = bh & 15;
    const bf16* Q  = qws  + (size_t)bh * T_SEQ * DHEAD;
    const bf16* K  = kws  + (size_t)bh * T_SEQ * DHEAD;
    const bf16* Vt = vtws + (size_t)bh * DHEAD * T_SEQ;

    const int tid = threadIdx.x, wid = tid >> 6, lane = tid & 63;
    const int lr = lane & 15, lg = lane >> 4;
    const int q0 = qt * 64 + wid * 16;

    // Q fragment, pre-scaled by 1/sqrt(DMODEL) = 2^-5 (exact in bf16)
    bf16x8 qf[2];
#pragma unroll
    for (int ks = 0; ks < 2; ++ks) {
        bf16x8 v = *(const bf16x8*)&Q[(size_t)(q0 + lr) * DHEAD + ks * 32 + lg * 8];
#pragma unroll
        for (int j = 0; j < 8; ++j) v[j] = (bf16)((float)v[j] * 0.03125f);
        qf[ks] = v;
    }

    f32x4 o[4];
#pragma unroll
    for (int nt = 0; nt < 4; ++nt) o[nt] = (f32x4)0.0f;
    float mrun = -1e30f, lrun = 0.f;   // per-lane stats for q-row = lr

    for (int kv0 = 0; kv0 < T_SEQ; kv0 += 64) {
        __syncthreads();
#pragma unroll
        for (int i = 0; i < 2; ++i) {
            int idx = i * 256 + tid;
            int row = idx >> 3, cb = (idx & 7) * 8;
            *(bf16x8*)&kls[row][cb] =
                *(const bf16x8*)&K[(size_t)(kv0 + row) * DHEAD + cb];
            *(bf16x8*)&vls[row][cb] =
                *(const bf16x8*)&Vt[(size_t)row * T_SEQ + kv0 + cb];
        }
        __syncthreads();

        // S^T tiles: s[nt][j] = S[q=lr][kv = nt*16 + 4*lg + j]  (pre-scaled)
        f32x4 s[4];
#pragma unroll
        for (int nt = 0; nt < 4; ++nt) {
            bf16x8 k0 = *(const bf16x8*)&kls[nt * 16 + lr][0 + lg * 8];
            bf16x8 k1 = *(const bf16x8*)&kls[nt * 16 + lr][32 + lg * 8];
            s[nt] = mfma16(k0, qf[0], (f32x4)0.0f);
            s[nt] = mfma16(k1, qf[1], s[nt]);
        }

        // row max: in-lane 16 values, then across the 4 lane groups
        float vm0 = fmaxf(fmaxf(s[0][0], s[0][1]), fmaxf(s[0][2], s[0][3]));
        float vm1 = fmaxf(fmaxf(s[1][0], s[1][1]), fmaxf(s[1][2], s[1][3]));
        float vm2 = fmaxf(fmaxf(s[2][0], s[2][1]), fmaxf(s[2][2], s[2][3]));
        float vm3 = fmaxf(fmaxf(s[3][0], s[3][1]), fmaxf(s[3][2], s[3][3]));
        float vm = fmaxf(fmaxf(vm0, vm1), fmaxf(vm2, vm3));
        vm = fmaxf(vm, __shfl_xor(vm, 16));
        vm = fmaxf(vm, __shfl_xor(vm, 32));

        float mnew = fmaxf(mrun, vm);
        float alpha = __expf(mrun - mnew);
        mrun = mnew;

        float p[4][4];
        float rs = 0.f;
#pragma unroll
        for (int nt = 0; nt < 4; ++nt)
#pragma unroll
            for (int j = 0; j < 4; ++j) {
                p[nt][j] = __expf(s[nt][j] - mnew);
                rs += p[nt][j];
            }
        rs += __shfl_xor(rs, 16);
        rs += __shfl_xor(rs, 32);
        lrun = lrun * alpha + rs;

        // store P (wave-private rows): packed dword writes
#pragma unroll
        for (int nt = 0; nt < 4; ++nt)
#pragma unroll
            for (int jj = 0; jj < 2; ++jj) {
                union { unsigned u; bf16 hh[2]; } pk;
                pk.hh[0] = (bf16)p[nt][2 * jj];
                pk.hh[1] = (bf16)p[nt][2 * jj + 1];
                *(unsigned*)&pls[wid * 16 + lr][nt * 16 + 4 * lg + 2 * jj] = pk.u;
            }

        // broadcast alpha to O-rows (o[nt][j] has q = 4*lg + j)
        float ab[4];
#pragma unroll
        for (int j = 0; j < 4; ++j) ab[j] = __shfl(alpha, lg * 4 + j);
#pragma unroll
        for (int nt = 0; nt < 4; ++nt)
#pragma unroll
            for (int j = 0; j < 4; ++j) o[nt][j] *= ab[j];

        // wave-local LDS visibility for pls (no cross-wave sharing)
        asm volatile("s_waitcnt lgkmcnt(0)" ::: "memory");

        // O += P V
#pragma unroll
        for (int ks = 0; ks < 2; ++ks) {
            bf16x8 pf = *(const bf16x8*)&pls[wid * 16 + lr][ks * 32 + lg * 8];
#pragma unroll
            for (int nt = 0; nt < 4; ++nt) {
                bf16x8 vf = *(const bf16x8*)&vls[nt * 16 + lr][ks * 32 + lg * 8];
                o[nt] = mfma16(pf, vf, o[nt]);
            }
        }
    }

    float linv[4];
#pragma unroll
    for (int j = 0; j < 4; ++j) linv[j] = 1.0f / __shfl(lrun, lg * 4 + j);

    const size_t obase = ((size_t)b * T_SEQ) * DMODEL + (size_t)h * DHEAD;
#pragma unroll
    for (int nt = 0; nt < 4; ++nt) {
        int d = nt * 16 + lr;
#pragma unroll
        for (int j = 0; j < 4; ++j) {
            int t = q0 + lg * 4 + j;
            aws[obase + (size_t)t * DMODEL + d] = (bf16)(o[nt][j] * linv[j]);
        }
    }
}

// ---------------------------------------------------------------------------
// Output projection: out = attn [4096,1024] @ Wo [1024,1024] + bo. (fp32 out)
// ---------------------------------------------------------------------------
__global__ __launch_bounds__(256) void out_gemm(
    const bf16* __restrict__ a, const bf16* __restrict__ wot,
    const float* __restrict__ bo, float* __restrict__ out)
{
    __shared__ __align__(16) bf16 as[128][72];
    __shared__ __align__(16) bf16 wsh[64][72];

    const int m0 = blockIdx.x * 128, n0 = blockIdx.y * 64;
    const int tid = threadIdx.x, wid = tid >> 6, lane = tid & 63;
    const int lr = lane & 15, lg = lane >> 4;

    f32x4 acc[2][4];
#pragma unroll
    for (int mi = 0; mi < 2; ++mi)
#pragma unroll
        for (int nt = 0; nt < 4; ++nt) acc[mi][nt] = (f32x4)0.0f;

    for (int kt = 0; kt < 16; ++kt) {
        const int kofs = kt * 64;
        __syncthreads();
#pragma unroll
        for (int i = 0; i < 4; ++i) {
            int idx = i * 256 + tid;
            int row = idx >> 3, cb = (idx & 7) * 8;
            *(bf16x8*)&as[row][cb] =
                *(const bf16x8*)&a[(size_t)(m0 + row) * DMODEL + kofs + cb];
        }
#pragma unroll
        for (int i = 0; i < 2; ++i) {
            int idx = i * 256 + tid;
            int row = idx >> 3, cb = (idx & 7) * 8;
            *(bf16x8*)&wsh[row][cb] =
                *(const bf16x8*)&wot[(size_t)(n0 + row) * DMODEL + kofs + cb];
        }
        __syncthreads();

        bf16x8 af[2][2];
#pragma unroll
        for (int mi = 0; mi < 2; ++mi)
#pragma unroll
            for (int ks = 0; ks < 2; ++ks)
                af[mi][ks] = *(const bf16x8*)&as[wid * 32 + mi * 16 + lr][ks * 32 + lg * 8];

#pragma unroll
        for (int nt = 0; nt < 4; ++nt)
#pragma unroll
            for (int ks = 0; ks < 2; ++ks) {
                bf16x8 bfr = *(const bf16x8*)&wsh[nt * 16 + lr][ks * 32 + lg * 8];
#pragma unroll
                for (int mi = 0; mi < 2; ++mi)
                    acc[mi][nt] = mfma16(af[mi][ks], bfr, acc[mi][nt]);
            }
    }

#pragma unroll
    for (int nt = 0; nt < 4; ++nt) {
        int n = n0 + nt * 16 + lr;
        float bs = bo[n];
#pragma unroll
        for (int mi = 0; mi < 2; ++mi)
#pragma unroll
            for (int j = 0; j < 4; ++j) {
                int m = m0 + wid * 32 + mi * 16 + lg * 4 + j;
                out[(size_t)m * DMODEL + n] = acc[mi][nt][j] + bs;
            }
    }
}

// ---------------------------------------------------------------------------
extern "C" void kernel_launch(void* const* d_in, const int* in_sizes, int n_in,
                              void* d_out, int out_size, void* d_ws, size_t ws_size,
                              hipStream_t stream)
{
    const float* x  = (const float*)d_in[0];
    const float* Wq = (const float*)d_in[1];
    const float* Wk = (const float*)d_in[2];
    const float* Wv = (const float*)d_in[3];
    const float* bq = (const float*)d_in[4];
    const float* bk = (const float*)d_in[5];
    const float* bv = (const float*)d_in[6];
    const float* Wo = (const float*)d_in[7];
    const float* bo = (const float*)d_in[8];
    float* out = (float*)d_out;

    const size_t M1 = (size_t)1024 * 1024;
    bf16* ws   = (bf16*)d_ws;
    bf16* xbf  = ws;                 // 4M elems [4096][1024]; reused as aws later
    bf16* qws  = ws + 4 * M1;        // 4M  [b,h,t,d]
    bf16* kws  = qws + 4 * M1;       // 4M  [b,h,t,d]
    bf16* vtws = kws + 4 * M1;       // 4M  [b,h,d,t]
    bf16* wt   = vtws + 4 * M1;      // 3M  [3*h][d][c]
    bf16* wot  = wt + 3 * M1;        // 1M  [n][k]
    bf16* aws  = xbf;                // alias: x dead after qkv_gemm
    // total: 20M bf16 = 40 MB

    dim3 tb(256);
    convert_f32_bf16<<<dim3(MTOT * DMODEL / (256 * 8)), tb, 0, stream>>>(x, xbf);
    transpose_f32_bf16<<<dim3(16, 1, 16), tb, 0, stream>>>(Wq, wt + 0 * M1, 1024, 64, 65536, 65536);
    transpose_f32_bf16<<<dim3(16, 1, 16), tb, 0, stream>>>(Wk, wt + 1 * M1, 1024, 64, 65536, 65536);
    transpose_f32_bf16<<<dim3(16, 1, 16), tb, 0, stream>>>(Wv, wt + 2 * M1, 1024, 64, 65536, 65536);
    transpose_f32_bf16<<<dim3(16, 16, 1), tb, 0, stream>>>(Wo, wot, 1024, 1024, 0, 0);

    qkv_gemm<<<dim3(MTOT / 128, NHEAD), tb, 0, stream>>>(xbf, wt, bq, bk, bv, qws, kws, vtws);
    attn_fused<<<dim3(T_SEQ / 64, 2 * NHEAD), tb, 0, stream>>>(qws, kws, vtws, aws);
    out_gemm<<<dim3(MTOT / 128, DMODEL / 64), tb, 0, stream>>>(aws, wot, bo, out);
}

// Round 5
// 168.253 us; speedup vs baseline: 1.2651x; 1.0636x over previous
//
#include <hip/hip_runtime.h>

typedef __bf16 bf16;
typedef __bf16 bf16x4 __attribute__((ext_vector_type(4)));
typedef __bf16 bf16x8 __attribute__((ext_vector_type(8)));
typedef float  f32x4  __attribute__((ext_vector_type(4)));

#define T_SEQ  2048
#define NHEAD  16
#define DHEAD  64
#define DMODEL 1024
#define MTOT   4096  // B*T
#define L2E    1.4426950408889634f

static __device__ __forceinline__ f32x4 mfma16(bf16x8 a, bf16x8 b, f32x4 c) {
    return __builtin_amdgcn_mfma_f32_16x16x32_bf16(a, b, c, 0, 0, 0);
}

// ---------------------------------------------------------------------------
// fp32 -> bf16 elementwise convert (8 elems/thread).
// ---------------------------------------------------------------------------
__global__ __launch_bounds__(256) void convert_f32_bf16(
    const float* __restrict__ in, bf16* __restrict__ out)
{
    const int i = blockIdx.x * 256 + threadIdx.x;   // index over 8-elem groups
    const float4 a = ((const float4*)in)[i * 2];
    const float4 b = ((const float4*)in)[i * 2 + 1];
    bf16x8 v;
    v[0] = (bf16)a.x; v[1] = (bf16)a.y; v[2] = (bf16)a.z; v[3] = (bf16)a.w;
    v[4] = (bf16)b.x; v[5] = (bf16)b.y; v[6] = (bf16)b.z; v[7] = (bf16)b.w;
    ((bf16x8*)out)[i] = v;
}

// ---------------------------------------------------------------------------
// 64x64-tiled transpose, fp32 in -> bf16 out: out[c][r] = (bf16)in[r][c].
// ---------------------------------------------------------------------------
__global__ __launch_bounds__(256) void transpose_f32_bf16(
    const float* __restrict__ in, bf16* __restrict__ out,
    int R, int Cc, long ibs, long obs)
{
    __shared__ float t[64][68];
    const int r0 = blockIdx.x * 64, c0 = blockIdx.y * 64;
    const long ib = ibs * (long)blockIdx.z, ob = obs * (long)blockIdx.z;
    const int tid = threadIdx.x;

#pragma unroll
    for (int i = 0; i < 4; ++i) {                   // load 64x64 fp32 tile
        int idx = i * 256 + tid;
        int row = idx >> 4, cb = (idx & 15) * 4;
        float4 v = *(const float4*)&in[ib + (long)(r0 + row) * Cc + c0 + cb];
        t[row][cb + 0] = v.x; t[row][cb + 1] = v.y;
        t[row][cb + 2] = v.z; t[row][cb + 3] = v.w;
    }
    __syncthreads();
#pragma unroll
    for (int i = 0; i < 2; ++i) {                   // store 64x64 bf16 transposed
        int idx = i * 256 + tid;
        int row = idx >> 3, cb = (idx & 7) * 8;     // row = out-row (col of in)
        bf16x8 v;
#pragma unroll
        for (int j = 0; j < 8; ++j) v[j] = (bf16)t[cb + j][row];
        *(bf16x8*)&out[ob + (long)(c0 + row) * R + r0 + cb] = v;
    }
}

// ---------------------------------------------------------------------------
// QKV projection: q/k/v[b,h,t,d] = x[b,t,:] @ W[h,:,d] + bias.
// ---------------------------------------------------------------------------
__global__ __launch_bounds__(256) void qkv_gemm(
    const bf16* __restrict__ x, const bf16* __restrict__ wt,
    const float* __restrict__ bq, const float* __restrict__ bk,
    const float* __restrict__ bv,
    bf16* __restrict__ qws, bf16* __restrict__ kws, bf16* __restrict__ vtws)
{
    __shared__ __align__(16) bf16 xs[128][72];
    __shared__ __align__(16) bf16 wsh[3][64][72];

    const int m0 = blockIdx.x * 128;
    const int h  = blockIdx.y;
    const int tid = threadIdx.x, wid = tid >> 6, lane = tid & 63;
    const int lr = lane & 15, lg = lane >> 4;

    const bf16* wbase[3];
#pragma unroll
    for (int w = 0; w < 3; ++w)
        wbase[w] = wt + ((size_t)(w * NHEAD + h)) * DHEAD * DMODEL;

    f32x4 acc[3][2][4];
#pragma unroll
    for (int w = 0; w < 3; ++w)
#pragma unroll
        for (int mi = 0; mi < 2; ++mi)
#pragma unroll
            for (int nt = 0; nt < 4; ++nt) acc[w][mi][nt] = (f32x4)0.0f;

    for (int kt = 0; kt < 16; ++kt) {
        const int kofs = kt * 64;
        __syncthreads();
#pragma unroll
        for (int i = 0; i < 4; ++i) {            // x tile: 128x64
            int idx = i * 256 + tid;
            int row = idx >> 3, cb = (idx & 7) * 8;
            *(bf16x8*)&xs[row][cb] =
                *(const bf16x8*)&x[(size_t)(m0 + row) * DMODEL + kofs + cb];
        }
#pragma unroll
        for (int w = 0; w < 3; ++w)
#pragma unroll
            for (int i = 0; i < 2; ++i) {        // wt tiles: 64x64 each
                int idx = i * 256 + tid;
                int row = idx >> 3, cb = (idx & 7) * 8;
                *(bf16x8*)&wsh[w][row][cb] =
                    *(const bf16x8*)&wbase[w][(size_t)row * DMODEL + kofs + cb];
            }
        __syncthreads();

        bf16x8 af[2][2];
#pragma unroll
        for (int mi = 0; mi < 2; ++mi)
#pragma unroll
            for (int ks = 0; ks < 2; ++ks)
                af[mi][ks] = *(const bf16x8*)&xs[wid * 32 + mi * 16 + lr][ks * 32 + lg * 8];

#pragma unroll
        for (int w = 0; w < 3; ++w)
#pragma unroll
            for (int nt = 0; nt < 4; ++nt)
#pragma unroll
                for (int ks = 0; ks < 2; ++ks) {
                    bf16x8 bfr = *(const bf16x8*)&wsh[w][nt * 16 + lr][ks * 32 + lg * 8];
#pragma unroll
                    for (int mi = 0; mi < 2; ++mi)
                        acc[w][mi][nt] = mfma16(af[mi][ks], bfr, acc[w][mi][nt]);
                }
    }

    const float* bias[3] = { bq + h * DHEAD, bk + h * DHEAD, bv + h * DHEAD };
#pragma unroll
    for (int w = 0; w < 3; ++w)
#pragma unroll
        for (int nt = 0; nt < 4; ++nt) {
            int d = nt * 16 + lr;
            float bs = bias[w][d];
#pragma unroll
            for (int mi = 0; mi < 2; ++mi)
#pragma unroll
                for (int j = 0; j < 4; ++j) {
                    int mrow = m0 + wid * 32 + mi * 16 + lg * 4 + j;
                    int b = mrow >> 11, t = mrow & 2047;
                    float val = acc[w][mi][nt][j] + bs;
                    size_t bh = (size_t)b * NHEAD + h;
                    if (w == 0)
                        qws[(bh * T_SEQ + t) * DHEAD + d] = (bf16)val;
                    else if (w == 1)
                        kws[(bh * T_SEQ + t) * DHEAD + d] = (bf16)val;
                    else
                        vtws[(bh * DHEAD + d) * T_SEQ + t] = (bf16)val;
                }
        }
}

// ---------------------------------------------------------------------------
// Fused flash attention, swapped-operand form + 2-phase pipelined KV loop.
// S^T = mfma(K_frag, Q_frag): each lane holds 16 kv-samples of q-row (lane&15).
// Double-buffered K/V staging: ONE barrier per KV-tile; next tile's global
// loads issued before compute so HBM/L2 latency hides under MFMA+softmax.
// exp2-direct softmax + defer-max (skip rescale unless max grows > 8).
// ---------------------------------------------------------------------------
__global__ __launch_bounds__(256) void attn_fused(
    const bf16* __restrict__ qws, const bf16* __restrict__ kws,
    const bf16* __restrict__ vtws, bf16* __restrict__ aws)
{
    __shared__ __align__(16) bf16 kls[2][64][72];
    __shared__ __align__(16) bf16 vls[2][64][72];
    __shared__ __align__(16) bf16 pls[64][72];

    const int qt = blockIdx.x;
    const int bh = blockIdx.y;
    const int b = bh >> 4, h = bh & 15;
    const bf16* Q  = qws  + (size_t)bh * T_SEQ * DHEAD;
    const bf16* K  = kws  + (size_t)bh * T_SEQ * DHEAD;
    const bf16* Vt = vtws + (size_t)bh * DHEAD * T_SEQ;

    const int tid = threadIdx.x, wid = tid >> 6, lane = tid & 63;
    const int lr = lane & 15, lg = lane >> 4;
    const int q0 = qt * 64 + wid * 16;

    // staging coords: thread covers rows (tid>>3) and 32+(tid>>3), col (tid&7)*8
    const int srow = tid >> 3, scb = (tid & 7) * 8;

    // Q fragment, pre-scaled by 1/sqrt(DMODEL) = 2^-5 (exact in bf16)
    bf16x8 qf[2];
#pragma unroll
    for (int ks = 0; ks < 2; ++ks) {
        bf16x8 v = *(const bf16x8*)&Q[(size_t)(q0 + lr) * DHEAD + ks * 32 + lg * 8];
#pragma unroll
        for (int j = 0; j < 8; ++j) v[j] = (bf16)((float)v[j] * 0.03125f);
        qf[ks] = v;
    }

    f32x4 o[4];
#pragma unroll
    for (int nt = 0; nt < 4; ++nt) o[nt] = (f32x4)0.0f;
    float mrun = -1e30f, lrun = 0.f;   // per-lane stats for q-row = lr

    // prologue: stage tile 0 into buf 0
    bf16x8 kr[2], vr[2];
#pragma unroll
    for (int i = 0; i < 2; ++i) {
        int row = srow + i * 32;
        kr[i] = *(const bf16x8*)&K[(size_t)row * DHEAD + scb];
        vr[i] = *(const bf16x8*)&Vt[(size_t)row * T_SEQ + scb];
    }
#pragma unroll
    for (int i = 0; i < 2; ++i) {
        int row = srow + i * 32;
        *(bf16x8*)&kls[0][row][scb] = kr[i];
        *(bf16x8*)&vls[0][row][scb] = vr[i];
    }

    int cur = 0;
    for (int t = 0; t < T_SEQ / 64; ++t) {
        __syncthreads();                     // buf[cur] writes visible to all

        // issue next tile's global loads (latency hides under compute)
        const bool more = (t + 1) < T_SEQ / 64;
        if (more) {
            int kvn = (t + 1) * 64;
#pragma unroll
            for (int i = 0; i < 2; ++i) {
                int row = srow + i * 32;
                kr[i] = *(const bf16x8*)&K[(size_t)(kvn + row) * DHEAD + scb];
                vr[i] = *(const bf16x8*)&Vt[(size_t)row * T_SEQ + kvn + scb];
            }
        }

        // S^T tiles: s[nt][j] = S[q=lr][kv = nt*16 + 4*lg + j]  (pre-scaled)
        f32x4 s[4];
#pragma unroll
        for (int nt = 0; nt < 4; ++nt) {
            bf16x8 k0 = *(const bf16x8*)&kls[cur][nt * 16 + lr][0 + lg * 8];
            bf16x8 k1 = *(const bf16x8*)&kls[cur][nt * 16 + lr][32 + lg * 8];
            s[nt] = mfma16(k0, qf[0], (f32x4)0.0f);
            s[nt] = mfma16(k1, qf[1], s[nt]);
        }

        // row max: in-lane 16 values, then across the 4 lane groups
        float vm0 = fmaxf(fmaxf(s[0][0], s[0][1]), fmaxf(s[0][2], s[0][3]));
        float vm1 = fmaxf(fmaxf(s[1][0], s[1][1]), fmaxf(s[1][2], s[1][3]));
        float vm2 = fmaxf(fmaxf(s[2][0], s[2][1]), fmaxf(s[2][2], s[2][3]));
        float vm3 = fmaxf(fmaxf(s[3][0], s[3][1]), fmaxf(s[3][2], s[3][3]));
        float vm = fmaxf(fmaxf(vm0, vm1), fmaxf(vm2, vm3));
        vm = fmaxf(vm, __shfl_xor(vm, 16));
        vm = fmaxf(vm, __shfl_xor(vm, 32));

        // defer-max: skip the O-rescale unless the max grew by > 8
        const bool skip = __all(vm <= mrun + 8.0f);
        float mnew = skip ? mrun : fmaxf(mrun, vm);
        float m2 = mnew * L2E;

        float p[4][4];
        float rs = 0.f;
#pragma unroll
        for (int nt = 0; nt < 4; ++nt)
#pragma unroll
            for (int j = 0; j < 4; ++j) {
                p[nt][j] = __builtin_amdgcn_exp2f(fmaf(s[nt][j], L2E, -m2));
                rs += p[nt][j];
            }
        rs += __shfl_xor(rs, 16);
        rs += __shfl_xor(rs, 32);

        if (skip) {
            lrun += rs;
        } else {
            float alpha = __builtin_amdgcn_exp2f((mrun - mnew) * L2E);
            lrun = lrun * alpha + rs;
            mrun = mnew;
            float ab[4];
#pragma unroll
            for (int j = 0; j < 4; ++j) ab[j] = __shfl(alpha, lg * 4 + j);
#pragma unroll
            for (int nt = 0; nt < 4; ++nt)
#pragma unroll
                for (int j = 0; j < 4; ++j) o[nt][j] *= ab[j];
        }

        // store P (wave-private rows): 4 x ds_write_b64
#pragma unroll
        for (int nt = 0; nt < 4; ++nt) {
            bf16x4 pk;
            pk[0] = (bf16)p[nt][0]; pk[1] = (bf16)p[nt][1];
            pk[2] = (bf16)p[nt][2]; pk[3] = (bf16)p[nt][3];
            *(bf16x4*)&pls[wid * 16 + lr][nt * 16 + 4 * lg] = pk;
        }

        // wave-local LDS visibility for pls (no cross-wave sharing)
        asm volatile("s_waitcnt lgkmcnt(0)" ::: "memory");

        // O += P V
#pragma unroll
        for (int ks = 0; ks < 2; ++ks) {
            bf16x8 pf = *(const bf16x8*)&pls[wid * 16 + lr][ks * 32 + lg * 8];
#pragma unroll
            for (int nt = 0; nt < 4; ++nt) {
                bf16x8 vf = *(const bf16x8*)&vls[cur][nt * 16 + lr][ks * 32 + lg * 8];
                o[nt] = mfma16(pf, vf, o[nt]);
            }
        }

        // write next tile into the other buffer (loads have had full compute
        // phase to land; implicit vmcnt wait covers them)
        if (more) {
#pragma unroll
            for (int i = 0; i < 2; ++i) {
                int row = srow + i * 32;
                *(bf16x8*)&kls[cur ^ 1][row][scb] = kr[i];
                *(bf16x8*)&vls[cur ^ 1][row][scb] = vr[i];
            }
        }
        cur ^= 1;
    }

    float linv[4];
#pragma unroll
    for (int j = 0; j < 4; ++j) linv[j] = 1.0f / __shfl(lrun, lg * 4 + j);

    const size_t obase = ((size_t)b * T_SEQ) * DMODEL + (size_t)h * DHEAD;
#pragma unroll
    for (int nt = 0; nt < 4; ++nt) {
        int d = nt * 16 + lr;
#pragma unroll
        for (int j = 0; j < 4; ++j) {
            int t = q0 + lg * 4 + j;
            aws[obase + (size_t)t * DMODEL + d] = (bf16)(o[nt][j] * linv[j]);
        }
    }
}

// ---------------------------------------------------------------------------
// Output projection: out = attn [4096,1024] @ Wo [1024,1024] + bo. (fp32 out)
// ---------------------------------------------------------------------------
__global__ __launch_bounds__(256) void out_gemm(
    const bf16* __restrict__ a, const bf16* __restrict__ wot,
    const float* __restrict__ bo, float* __restrict__ out)
{
    __shared__ __align__(16) bf16 as[128][72];
    __shared__ __align__(16) bf16 wsh[64][72];

    const int m0 = blockIdx.x * 128, n0 = blockIdx.y * 64;
    const int tid = threadIdx.x, wid = tid >> 6, lane = tid & 63;
    const int lr = lane & 15, lg = lane >> 4;

    f32x4 acc[2][4];
#pragma unroll
    for (int mi = 0; mi < 2; ++mi)
#pragma unroll
        for (int nt = 0; nt < 4; ++nt) acc[mi][nt] = (f32x4)0.0f;

    for (int kt = 0; kt < 16; ++kt) {
        const int kofs = kt * 64;
        __syncthreads();
#pragma unroll
        for (int i = 0; i < 4; ++i) {
            int idx = i * 256 + tid;
            int row = idx >> 3, cb = (idx & 7) * 8;
            *(bf16x8*)&as[row][cb] =
                *(const bf16x8*)&a[(size_t)(m0 + row) * DMODEL + kofs + cb];
        }
#pragma unroll
        for (int i = 0; i < 2; ++i) {
            int idx = i * 256 + tid;
            int row = idx >> 3, cb = (idx & 7) * 8;
            *(bf16x8*)&wsh[row][cb] =
                *(const bf16x8*)&wot[(size_t)(n0 + row) * DMODEL + kofs + cb];
        }
        __syncthreads();

        bf16x8 af[2][2];
#pragma unroll
        for (int mi = 0; mi < 2; ++mi)
#pragma unroll
            for (int ks = 0; ks < 2; ++ks)
                af[mi][ks] = *(const bf16x8*)&as[wid * 32 + mi * 16 + lr][ks * 32 + lg * 8];

#pragma unroll
        for (int nt = 0; nt < 4; ++nt)
#pragma unroll
            for (int ks = 0; ks < 2; ++ks) {
                bf16x8 bfr = *(const bf16x8*)&wsh[nt * 16 + lr][ks * 32 + lg * 8];
#pragma unroll
                for (int mi = 0; mi < 2; ++mi)
                    acc[mi][nt] = mfma16(af[mi][ks], bfr, acc[mi][nt]);
            }
    }

#pragma unroll
    for (int nt = 0; nt < 4; ++nt) {
        int n = n0 + nt * 16 + lr;
        float bs = bo[n];
#pragma unroll
        for (int mi = 0; mi < 2; ++mi)
#pragma unroll
            for (int j = 0; j < 4; ++j) {
                int m = m0 + wid * 32 + mi * 16 + lg * 4 + j;
                out[(size_t)m * DMODEL + n] = acc[mi][nt][j] + bs;
            }
    }
}

// ---------------------------------------------------------------------------
extern "C" void kernel_launch(void* const* d_in, const int* in_sizes, int n_in,
                              void* d_out, int out_size, void* d_ws, size_t ws_size,
                              hipStream_t stream)
{
    const float* x  = (const float*)d_in[0];
    const float* Wq = (const float*)d_in[1];
    const float* Wk = (const float*)d_in[2];
    const float* Wv = (const float*)d_in[3];
    const float* bq = (const float*)d_in[4];
    const float* bk = (const float*)d_in[5];
    const float* bv = (const float*)d_in[6];
    const float* Wo = (const float*)d_in[7];
    const float* bo = (const float*)d_in[8];
    float* out = (float*)d_out;

    const size_t M1 = (size_t)1024 * 1024;
    bf16* ws   = (bf16*)d_ws;
    bf16* xbf  = ws;                 // 4M elems [4096][1024]; reused as aws later
    bf16* qws  = ws + 4 * M1;        // 4M  [b,h,t,d]
    bf16* kws  = qws + 4 * M1;       // 4M  [b,h,t,d]
    bf16* vtws = kws + 4 * M1;       // 4M  [b,h,d,t]
    bf16* wt   = vtws + 4 * M1;      // 3M  [3*h][d][c]
    bf16* wot  = wt + 3 * M1;        // 1M  [n][k]
    bf16* aws  = xbf;                // alias: x dead after qkv_gemm
    // total: 20M bf16 = 40 MB

    dim3 tb(256);
    convert_f32_bf16<<<dim3(MTOT * DMODEL / (256 * 8)), tb, 0, stream>>>(x, xbf);
    transpose_f32_bf16<<<dim3(16, 1, 16), tb, 0, stream>>>(Wq, wt + 0 * M1, 1024, 64, 65536, 65536);
    transpose_f32_bf16<<<dim3(16, 1, 16), tb, 0, stream>>>(Wk, wt + 1 * M1, 1024, 64, 65536, 65536);
    transpose_f32_bf16<<<dim3(16, 1, 16), tb, 0, stream>>>(Wv, wt + 2 * M1, 1024, 64, 65536, 65536);
    transpose_f32_bf16<<<dim3(16, 16, 1), tb, 0, stream>>>(Wo, wot, 1024, 1024, 0, 0);

    qkv_gemm<<<dim3(MTOT / 128, NHEAD), tb, 0, stream>>>(xbf, wt, bq, bk, bv, qws, kws, vtws);
    attn_fused<<<dim3(T_SEQ / 64, 2 * NHEAD), tb, 0, stream>>>(qws, kws, vtws, aws);
    out_gemm<<<dim3(MTOT / 128, DMODEL / 64), tb, 0, stream>>>(aws, wot, bo, out);
}

// Round 6
// 153.363 us; speedup vs baseline: 1.3879x; 1.0971x over previous
//
#include <hip/hip_runtime.h>

typedef __bf16 bf16;
typedef __bf16 bf16x4 __attribute__((ext_vector_type(4)));
typedef __bf16 bf16x8 __attribute__((ext_vector_type(8)));
typedef float  f32x4  __attribute__((ext_vector_type(4)));

#define T_SEQ  2048
#define NHEAD  16
#define DHEAD  64
#define DMODEL 1024
#define MTOT   4096  // B*T
#define L2E    1.4426950408889634f

static __device__ __forceinline__ f32x4 mfma16(bf16x8 a, bf16x8 b, f32x4 c) {
    return __builtin_amdgcn_mfma_f32_16x16x32_bf16(a, b, c, 0, 0, 0);
}

// ---------------------------------------------------------------------------
// fp32 -> bf16 elementwise convert (8 elems/thread).
// ---------------------------------------------------------------------------
__global__ __launch_bounds__(256) void convert_f32_bf16(
    const float* __restrict__ in, bf16* __restrict__ out)
{
    const int i = blockIdx.x * 256 + threadIdx.x;   // index over 8-elem groups
    const float4 a = ((const float4*)in)[i * 2];
    const float4 b = ((const float4*)in)[i * 2 + 1];
    bf16x8 v;
    v[0] = (bf16)a.x; v[1] = (bf16)a.y; v[2] = (bf16)a.z; v[3] = (bf16)a.w;
    v[4] = (bf16)b.x; v[5] = (bf16)b.y; v[6] = (bf16)b.z; v[7] = (bf16)b.w;
    ((bf16x8*)out)[i] = v;
}

// ---------------------------------------------------------------------------
// 64x64-tiled transpose, fp32 in -> bf16 out: out[c][r] = (bf16)in[r][c].
// ---------------------------------------------------------------------------
__global__ __launch_bounds__(256) void transpose_f32_bf16(
    const float* __restrict__ in, bf16* __restrict__ out,
    int R, int Cc, long ibs, long obs)
{
    __shared__ float t[64][68];
    const int r0 = blockIdx.x * 64, c0 = blockIdx.y * 64;
    const long ib = ibs * (long)blockIdx.z, ob = obs * (long)blockIdx.z;
    const int tid = threadIdx.x;

#pragma unroll
    for (int i = 0; i < 4; ++i) {                   // load 64x64 fp32 tile
        int idx = i * 256 + tid;
        int row = idx >> 4, cb = (idx & 15) * 4;
        float4 v = *(const float4*)&in[ib + (long)(r0 + row) * Cc + c0 + cb];
        t[row][cb + 0] = v.x; t[row][cb + 1] = v.y;
        t[row][cb + 2] = v.z; t[row][cb + 3] = v.w;
    }
    __syncthreads();
#pragma unroll
    for (int i = 0; i < 2; ++i) {                   // store 64x64 bf16 transposed
        int idx = i * 256 + tid;
        int row = idx >> 3, cb = (idx & 7) * 8;     // row = out-row (col of in)
        bf16x8 v;
#pragma unroll
        for (int j = 0; j < 8; ++j) v[j] = (bf16)t[cb + j][row];
        *(bf16x8*)&out[ob + (long)(c0 + row) * R + r0 + cb] = v;
    }
}

// ---------------------------------------------------------------------------
// QKV projection: q/k/v[b,h,t,d] = x[b,t,:] @ W[h,:,d] + bias.
// ---------------------------------------------------------------------------
__global__ __launch_bounds__(256) void qkv_gemm(
    const bf16* __restrict__ x, const bf16* __restrict__ wt,
    const float* __restrict__ bq, const float* __restrict__ bk,
    const float* __restrict__ bv,
    bf16* __restrict__ qws, bf16* __restrict__ kws, bf16* __restrict__ vtws)
{
    __shared__ __align__(16) bf16 xs[128][72];
    __shared__ __align__(16) bf16 wsh[3][64][72];

    const int m0 = blockIdx.x * 128;
    const int h  = blockIdx.y;
    const int tid = threadIdx.x, wid = tid >> 6, lane = tid & 63;
    const int lr = lane & 15, lg = lane >> 4;

    const bf16* wbase[3];
#pragma unroll
    for (int w = 0; w < 3; ++w)
        wbase[w] = wt + ((size_t)(w * NHEAD + h)) * DHEAD * DMODEL;

    f32x4 acc[3][2][4];
#pragma unroll
    for (int w = 0; w < 3; ++w)
#pragma unroll
        for (int mi = 0; mi < 2; ++mi)
#pragma unroll
            for (int nt = 0; nt < 4; ++nt) acc[w][mi][nt] = (f32x4)0.0f;

    for (int kt = 0; kt < 16; ++kt) {
        const int kofs = kt * 64;
        __syncthreads();
#pragma unroll
        for (int i = 0; i < 4; ++i) {            // x tile: 128x64
            int idx = i * 256 + tid;
            int row = idx >> 3, cb = (idx & 7) * 8;
            *(bf16x8*)&xs[row][cb] =
                *(const bf16x8*)&x[(size_t)(m0 + row) * DMODEL + kofs + cb];
        }
#pragma unroll
        for (int w = 0; w < 3; ++w)
#pragma unroll
            for (int i = 0; i < 2; ++i) {        // wt tiles: 64x64 each
                int idx = i * 256 + tid;
                int row = idx >> 3, cb = (idx & 7) * 8;
                *(bf16x8*)&wsh[w][row][cb] =
                    *(const bf16x8*)&wbase[w][(size_t)row * DMODEL + kofs + cb];
            }
        __syncthreads();

        bf16x8 af[2][2];
#pragma unroll
        for (int mi = 0; mi < 2; ++mi)
#pragma unroll
            for (int ks = 0; ks < 2; ++ks)
                af[mi][ks] = *(const bf16x8*)&xs[wid * 32 + mi * 16 + lr][ks * 32 + lg * 8];

#pragma unroll
        for (int w = 0; w < 3; ++w)
#pragma unroll
            for (int nt = 0; nt < 4; ++nt)
#pragma unroll
                for (int ks = 0; ks < 2; ++ks) {
                    bf16x8 bfr = *(const bf16x8*)&wsh[w][nt * 16 + lr][ks * 32 + lg * 8];
#pragma unroll
                    for (int mi = 0; mi < 2; ++mi)
                        acc[w][mi][nt] = mfma16(af[mi][ks], bfr, acc[w][mi][nt]);
                }
    }

    const float* bias[3] = { bq + h * DHEAD, bk + h * DHEAD, bv + h * DHEAD };
#pragma unroll
    for (int w = 0; w < 3; ++w)
#pragma unroll
        for (int nt = 0; nt < 4; ++nt) {
            int d = nt * 16 + lr;
            float bs = bias[w][d];
#pragma unroll
            for (int mi = 0; mi < 2; ++mi)
#pragma unroll
                for (int j = 0; j < 4; ++j) {
                    int mrow = m0 + wid * 32 + mi * 16 + lg * 4 + j;
                    int b = mrow >> 11, t = mrow & 2047;
                    float val = acc[w][mi][nt][j] + bs;
                    size_t bh = (size_t)b * NHEAD + h;
                    if (w == 0)
                        qws[(bh * T_SEQ + t) * DHEAD + d] = (bf16)val;
                    else if (w == 1)
                        kws[(bh * T_SEQ + t) * DHEAD + d] = (bf16)val;
                    else
                        vtws[(bh * DHEAD + d) * T_SEQ + t] = (bf16)val;
                }
        }
}

// ---------------------------------------------------------------------------
// Fused flash attention, swapped-operand form + 2-phase pipelined KV loop.
// Block = 8 waves (512 threads) covering 128 q-rows; one shared K/V tile
// stream serves all 8 waves (staging per-thread halves, FETCH halves).
// S^T = mfma(K_frag, Q_frag); exp2-direct softmax; defer-max rescale.
// ---------------------------------------------------------------------------
__global__ __launch_bounds__(512) void attn_fused(
    const bf16* __restrict__ qws, const bf16* __restrict__ kws,
    const bf16* __restrict__ vtws, bf16* __restrict__ aws)
{
    __shared__ __align__(16) bf16 kls[2][64][72];
    __shared__ __align__(16) bf16 vls[2][64][72];
    __shared__ __align__(16) bf16 pls[128][72];

    const int qt = blockIdx.x;
    const int bh = blockIdx.y;
    const int b = bh >> 4, h = bh & 15;
    const bf16* Q  = qws  + (size_t)bh * T_SEQ * DHEAD;
    const bf16* K  = kws  + (size_t)bh * T_SEQ * DHEAD;
    const bf16* Vt = vtws + (size_t)bh * DHEAD * T_SEQ;

    const int tid = threadIdx.x, wid = tid >> 6, lane = tid & 63;
    const int lr = lane & 15, lg = lane >> 4;
    const int q0 = qt * 128 + wid * 16;

    // staging coords: 512 threads cover the 64x64 tile once (1 b128 K + 1 V)
    const int srow = tid >> 3, scb = (tid & 7) * 8;

    // Q fragment, pre-scaled by 1/sqrt(DMODEL) = 2^-5 (exact in bf16)
    bf16x8 qf[2];
#pragma unroll
    for (int ks = 0; ks < 2; ++ks) {
        bf16x8 v = *(const bf16x8*)&Q[(size_t)(q0 + lr) * DHEAD + ks * 32 + lg * 8];
#pragma unroll
        for (int j = 0; j < 8; ++j) v[j] = (bf16)((float)v[j] * 0.03125f);
        qf[ks] = v;
    }

    f32x4 o[4];
#pragma unroll
    for (int nt = 0; nt < 4; ++nt) o[nt] = (f32x4)0.0f;
    float mrun = -1e30f, lrun = 0.f;   // per-lane stats for q-row = lr

    // prologue: stage tile 0 into buf 0
    bf16x8 kr, vr;
    kr = *(const bf16x8*)&K[(size_t)srow * DHEAD + scb];
    vr = *(const bf16x8*)&Vt[(size_t)srow * T_SEQ + scb];
    *(bf16x8*)&kls[0][srow][scb] = kr;
    *(bf16x8*)&vls[0][srow][scb] = vr;

    int cur = 0;
    for (int t = 0; t < T_SEQ / 64; ++t) {
        __syncthreads();                     // buf[cur] writes visible to all

        // issue next tile's global loads (latency hides under compute)
        const bool more = (t + 1) < T_SEQ / 64;
        if (more) {
            int kvn = (t + 1) * 64;
            kr = *(const bf16x8*)&K[(size_t)(kvn + srow) * DHEAD + scb];
            vr = *(const bf16x8*)&Vt[(size_t)srow * T_SEQ + kvn + scb];
        }

        // S^T tiles: s[nt][j] = S[q=lr][kv = nt*16 + 4*lg + j]  (pre-scaled)
        f32x4 s[4];
#pragma unroll
        for (int nt = 0; nt < 4; ++nt) {
            bf16x8 k0 = *(const bf16x8*)&kls[cur][nt * 16 + lr][0 + lg * 8];
            bf16x8 k1 = *(const bf16x8*)&kls[cur][nt * 16 + lr][32 + lg * 8];
            s[nt] = mfma16(k0, qf[0], (f32x4)0.0f);
            s[nt] = mfma16(k1, qf[1], s[nt]);
        }

        // row max: in-lane 16 values, then across the 4 lane groups
        float vm0 = fmaxf(fmaxf(s[0][0], s[0][1]), fmaxf(s[0][2], s[0][3]));
        float vm1 = fmaxf(fmaxf(s[1][0], s[1][1]), fmaxf(s[1][2], s[1][3]));
        float vm2 = fmaxf(fmaxf(s[2][0], s[2][1]), fmaxf(s[2][2], s[2][3]));
        float vm3 = fmaxf(fmaxf(s[3][0], s[3][1]), fmaxf(s[3][2], s[3][3]));
        float vm = fmaxf(fmaxf(vm0, vm1), fmaxf(vm2, vm3));
        vm = fmaxf(vm, __shfl_xor(vm, 16));
        vm = fmaxf(vm, __shfl_xor(vm, 32));

        // defer-max: skip the O-rescale unless the max grew by > 8
        const bool skip = __all(vm <= mrun + 8.0f);
        float mnew = skip ? mrun : fmaxf(mrun, vm);
        float m2 = mnew * L2E;

        float p[4][4];
        float rs = 0.f;
#pragma unroll
        for (int nt = 0; nt < 4; ++nt)
#pragma unroll
            for (int j = 0; j < 4; ++j) {
                p[nt][j] = __builtin_amdgcn_exp2f(fmaf(s[nt][j], L2E, -m2));
                rs += p[nt][j];
            }
        rs += __shfl_xor(rs, 16);
        rs += __shfl_xor(rs, 32);

        if (skip) {
            lrun += rs;
        } else {
            float alpha = __builtin_amdgcn_exp2f((mrun - mnew) * L2E);
            lrun = lrun * alpha + rs;
            mrun = mnew;
            float ab[4];
#pragma unroll
            for (int j = 0; j < 4; ++j) ab[j] = __shfl(alpha, lg * 4 + j);
#pragma unroll
            for (int nt = 0; nt < 4; ++nt)
#pragma unroll
                for (int j = 0; j < 4; ++j) o[nt][j] *= ab[j];
        }

        // store P (wave-private rows): 4 x ds_write_b64
#pragma unroll
        for (int nt = 0; nt < 4; ++nt) {
            bf16x4 pk;
            pk[0] = (bf16)p[nt][0]; pk[1] = (bf16)p[nt][1];
            pk[2] = (bf16)p[nt][2]; pk[3] = (bf16)p[nt][3];
            *(bf16x4*)&pls[wid * 16 + lr][nt * 16 + 4 * lg] = pk;
        }

        // wave-local LDS visibility for pls (no cross-wave sharing)
        asm volatile("s_waitcnt lgkmcnt(0)" ::: "memory");

        // O += P V
#pragma unroll
        for (int ks = 0; ks < 2; ++ks) {
            bf16x8 pf = *(const bf16x8*)&pls[wid * 16 + lr][ks * 32 + lg * 8];
#pragma unroll
            for (int nt = 0; nt < 4; ++nt) {
                bf16x8 vf = *(const bf16x8*)&vls[cur][nt * 16 + lr][ks * 32 + lg * 8];
                o[nt] = mfma16(pf, vf, o[nt]);
            }
        }

        // write next tile into the other buffer (loads have had full compute
        // phase to land; implicit vmcnt wait covers them)
        if (more) {
            *(bf16x8*)&kls[cur ^ 1][srow][scb] = kr;
            *(bf16x8*)&vls[cur ^ 1][srow][scb] = vr;
        }
        cur ^= 1;
    }

    float linv[4];
#pragma unroll
    for (int j = 0; j < 4; ++j) linv[j] = 1.0f / __shfl(lrun, lg * 4 + j);

    const size_t obase = ((size_t)b * T_SEQ) * DMODEL + (size_t)h * DHEAD;
#pragma unroll
    for (int nt = 0; nt < 4; ++nt) {
        int d = nt * 16 + lr;
#pragma unroll
        for (int j = 0; j < 4; ++j) {
            int t = q0 + lg * 4 + j;
            aws[obase + (size_t)t * DMODEL + d] = (bf16)(o[nt][j] * linv[j]);
        }
    }
}

// ---------------------------------------------------------------------------
// Output projection: out = attn [4096,1024] @ Wo [1024,1024] + bo. (fp32 out)
// ---------------------------------------------------------------------------
__global__ __launch_bounds__(256) void out_gemm(
    const bf16* __restrict__ a, const bf16* __restrict__ wot,
    const float* __restrict__ bo, float* __restrict__ out)
{
    __shared__ __align__(16) bf16 as[128][72];
    __shared__ __align__(16) bf16 wsh[64][72];

    const int m0 = blockIdx.x * 128, n0 = blockIdx.y * 64;
    const int tid = threadIdx.x, wid = tid >> 6, lane = tid & 63;
    const int lr = lane & 15, lg = lane >> 4;

    f32x4 acc[2][4];
#pragma unroll
    for (int mi = 0; mi < 2; ++mi)
#pragma unroll
        for (int nt = 0; nt < 4; ++nt) acc[mi][nt] = (f32x4)0.0f;

    for (int kt = 0; kt < 16; ++kt) {
        const int kofs = kt * 64;
        __syncthreads();
#pragma unroll
        for (int i = 0; i < 4; ++i) {
            int idx = i * 256 + tid;
            int row = idx >> 3, cb = (idx & 7) * 8;
            *(bf16x8*)&as[row][cb] =
                *(const bf16x8*)&a[(size_t)(m0 + row) * DMODEL + kofs + cb];
        }
#pragma unroll
        for (int i = 0; i < 2; ++i) {
            int idx = i * 256 + tid;
            int row = idx >> 3, cb = (idx & 7) * 8;
            *(bf16x8*)&wsh[row][cb] =
                *(const bf16x8*)&wot[(size_t)(n0 + row) * DMODEL + kofs + cb];
        }
        __syncthreads();

        bf16x8 af[2][2];
#pragma unroll
        for (int mi = 0; mi < 2; ++mi)
#pragma unroll
            for (int ks = 0; ks < 2; ++ks)
                af[mi][ks] = *(const bf16x8*)&as[wid * 32 + mi * 16 + lr][ks * 32 + lg * 8];

#pragma unroll
        for (int nt = 0; nt < 4; ++nt)
#pragma unroll
            for (int ks = 0; ks < 2; ++ks) {
                bf16x8 bfr = *(const bf16x8*)&wsh[nt * 16 + lr][ks * 32 + lg * 8];
#pragma unroll
                for (int mi = 0; mi < 2; ++mi)
                    acc[mi][nt] = mfma16(af[mi][ks], bfr, acc[mi][nt]);
            }
    }

#pragma unroll
    for (int nt = 0; nt < 4; ++nt) {
        int n = n0 + nt * 16 + lr;
        float bs = bo[n];
#pragma unroll
        for (int mi = 0; mi < 2; ++mi)
#pragma unroll
            for (int j = 0; j < 4; ++j) {
                int m = m0 + wid * 32 + mi * 16 + lg * 4 + j;
                out[(size_t)m * DMODEL + n] = acc[mi][nt][j] + bs;
            }
    }
}

// ---------------------------------------------------------------------------
extern "C" void kernel_launch(void* const* d_in, const int* in_sizes, int n_in,
                              void* d_out, int out_size, void* d_ws, size_t ws_size,
                              hipStream_t stream)
{
    const float* x  = (const float*)d_in[0];
    const float* Wq = (const float*)d_in[1];
    const float* Wk = (const float*)d_in[2];
    const float* Wv = (const float*)d_in[3];
    const float* bq = (const float*)d_in[4];
    const float* bk = (const float*)d_in[5];
    const float* bv = (const float*)d_in[6];
    const float* Wo = (const float*)d_in[7];
    const float* bo = (const float*)d_in[8];
    float* out = (float*)d_out;

    const size_t M1 = (size_t)1024 * 1024;
    bf16* ws   = (bf16*)d_ws;
    bf16* xbf  = ws;                 // 4M elems [4096][1024]; reused as aws later
    bf16* qws  = ws + 4 * M1;        // 4M  [b,h,t,d]
    bf16* kws  = qws + 4 * M1;       // 4M  [b,h,t,d]
    bf16* vtws = kws + 4 * M1;       // 4M  [b,h,d,t]
    bf16* wt   = vtws + 4 * M1;      // 3M  [3*h][d][c]
    bf16* wot  = wt + 3 * M1;        // 1M  [n][k]
    bf16* aws  = xbf;                // alias: x dead after qkv_gemm
    // total: 20M bf16 = 40 MB

    dim3 tb(256);
    convert_f32_bf16<<<dim3(MTOT * DMODEL / (256 * 8)), tb, 0, stream>>>(x, xbf);
    transpose_f32_bf16<<<dim3(16, 1, 16), tb, 0, stream>>>(Wq, wt + 0 * M1, 1024, 64, 65536, 65536);
    transpose_f32_bf16<<<dim3(16, 1, 16), tb, 0, stream>>>(Wk, wt + 1 * M1, 1024, 64, 65536, 65536);
    transpose_f32_bf16<<<dim3(16, 1, 16), tb, 0, stream>>>(Wv, wt + 2 * M1, 1024, 64, 65536, 65536);
    transpose_f32_bf16<<<dim3(16, 16, 1), tb, 0, stream>>>(Wo, wot, 1024, 1024, 0, 0);

    qkv_gemm<<<dim3(MTOT / 128, NHEAD), tb, 0, stream>>>(xbf, wt, bq, bk, bv, qws, kws, vtws);
    attn_fused<<<dim3(T_SEQ / 128, 2 * NHEAD), dim3(512), 0, stream>>>(qws, kws, vtws, aws);
    out_gemm<<<dim3(MTOT / 128, DMODEL / 64), tb, 0, stream>>>(aws, wot, bo, out);
}

// Round 7
// 128.698 us; speedup vs baseline: 1.6539x; 1.1916x over previous
//
#include <hip/hip_runtime.h>

typedef __bf16 bf16;
typedef __bf16 bf16x4 __attribute__((ext_vector_type(4)));
typedef __bf16 bf16x8 __attribute__((ext_vector_type(8)));
typedef float  f32x4  __attribute__((ext_vector_type(4)));

#define T_SEQ  2048
#define NHEAD  16
#define DHEAD  64
#define DMODEL 1024
#define MTOT   4096  // B*T
#define L2E    1.4426950408889634f

static __device__ __forceinline__ f32x4 mfma16(bf16x8 a, bf16x8 b, f32x4 c) {
    return __builtin_amdgcn_mfma_f32_16x16x32_bf16(a, b, c, 0, 0, 0);
}

// ---------------------------------------------------------------------------
// prep: one kernel for all preprocessing.
//   blocks [0, 2048)        : x fp32 -> bf16 convert (8 elems/thread)
//   blocks [2048, 2816)     : Wq/Wk/Wv transpose  [1024,64] -> [64,1024] bf16
//   blocks [2816, 3072)     : Wo transpose        [1024,1024] -> [1024,1024]^T
// ---------------------------------------------------------------------------
__global__ __launch_bounds__(256) void prep(
    const float* __restrict__ x,  bf16* __restrict__ xbf,
    const float* __restrict__ Wq, const float* __restrict__ Wk,
    const float* __restrict__ Wv, bf16* __restrict__ wt,
    const float* __restrict__ Wo, bf16* __restrict__ wot)
{
    __shared__ float t[64][68];
    const int bid = blockIdx.x, tid = threadIdx.x;

    if (bid < 2048) {                 // ---- convert x ----
        const int i = bid * 256 + tid;
        const float4 a = ((const float4*)x)[i * 2];
        const float4 b = ((const float4*)x)[i * 2 + 1];
        bf16x8 v;
        v[0] = (bf16)a.x; v[1] = (bf16)a.y; v[2] = (bf16)a.z; v[3] = (bf16)a.w;
        v[4] = (bf16)b.x; v[5] = (bf16)b.y; v[6] = (bf16)b.z; v[7] = (bf16)b.w;
        ((bf16x8*)xbf)[i] = v;
        return;
    }

    // ---- transposes ----
    const float* in; bf16* out;
    int R, Cc; long ib, ob; int r0, c0;
    if (bid < 2816) {
        int b2 = bid - 2048;
        int w = b2 >> 8, rem = b2 & 255;          // w in 0..2, rem in 0..255
        int rt = rem & 15, head = rem >> 4;
        in  = (w == 0 ? Wq : w == 1 ? Wk : Wv);
        out = wt + (size_t)w * 1024 * 1024;
        R = 1024; Cc = 64;
        ib = (long)head * 65536; ob = (long)head * 65536;
        r0 = rt * 64; c0 = 0;
    } else {
        int b3 = bid - 2816;
        in = Wo; out = wot;
        R = 1024; Cc = 1024;
        ib = 0; ob = 0;
        r0 = (b3 & 15) * 64; c0 = (b3 >> 4) * 64;
    }

#pragma unroll
    for (int i = 0; i < 4; ++i) {                 // load 64x64 fp32 tile
        int idx = i * 256 + tid;
        int row = idx >> 4, cb = (idx & 15) * 4;
        float4 v = *(const float4*)&in[ib + (long)(r0 + row) * Cc + c0 + cb];
        t[row][cb + 0] = v.x; t[row][cb + 1] = v.y;
        t[row][cb + 2] = v.z; t[row][cb + 3] = v.w;
    }
    __syncthreads();
#pragma unroll
    for (int i = 0; i < 2; ++i) {                 // store 64x64 bf16 transposed
        int idx = i * 256 + tid;
        int row = idx >> 3, cb = (idx & 7) * 8;   // row = out-row (col of in)
        bf16x8 v;
#pragma unroll
        for (int j = 0; j < 8; ++j) v[j] = (bf16)t[cb + j][row];
        *(bf16x8*)&out[ob + (long)(c0 + row) * R + r0 + cb] = v;
    }
}

// ---------------------------------------------------------------------------
// QKV projection with T14 register-prefetch pipeline:
// issue step k+1's global loads after the compute barrier; ds_write them at
// the top of the next iteration (latency hides under the 32-MFMA phase).
// ---------------------------------------------------------------------------
__global__ __launch_bounds__(256) void qkv_gemm(
    const bf16* __restrict__ x, const bf16* __restrict__ wt,
    const float* __restrict__ bq, const float* __restrict__ bk,
    const float* __restrict__ bv,
    bf16* __restrict__ qws, bf16* __restrict__ kws, bf16* __restrict__ vtws)
{
    __shared__ __align__(16) bf16 xs[128][72];
    __shared__ __align__(16) bf16 wsh[3][64][72];

    const int m0 = blockIdx.x * 128;
    const int h  = blockIdx.y;
    const int tid = threadIdx.x, wid = tid >> 6, lane = tid & 63;
    const int lr = lane & 15, lg = lane >> 4;

    const bf16* wbase[3];
#pragma unroll
    for (int w = 0; w < 3; ++w)
        wbase[w] = wt + ((size_t)(w * NHEAD + h)) * DHEAD * DMODEL;

    f32x4 acc[3][2][4];
#pragma unroll
    for (int w = 0; w < 3; ++w)
#pragma unroll
        for (int mi = 0; mi < 2; ++mi)
#pragma unroll
            for (int nt = 0; nt < 4; ++nt) acc[w][mi][nt] = (f32x4)0.0f;

    // staging reg prefetch: x 4 x b128, w 3x2 x b128 per thread
    bf16x8 xr[4], wr[3][2];
#pragma unroll
    for (int i = 0; i < 4; ++i) {
        int idx = i * 256 + tid;
        int row = idx >> 3, cb = (idx & 7) * 8;
        xr[i] = *(const bf16x8*)&x[(size_t)(m0 + row) * DMODEL + cb];
    }
#pragma unroll
    for (int w = 0; w < 3; ++w)
#pragma unroll
        for (int i = 0; i < 2; ++i) {
            int idx = i * 256 + tid;
            int row = idx >> 3, cb = (idx & 7) * 8;
            wr[w][i] = *(const bf16x8*)&wbase[w][(size_t)row * DMODEL + cb];
        }

    for (int kt = 0; kt < 16; ++kt) {
        __syncthreads();                 // previous compute done reading LDS
#pragma unroll
        for (int i = 0; i < 4; ++i) {
            int idx = i * 256 + tid;
            int row = idx >> 3, cb = (idx & 7) * 8;
            *(bf16x8*)&xs[row][cb] = xr[i];
        }
#pragma unroll
        for (int w = 0; w < 3; ++w)
#pragma unroll
            for (int i = 0; i < 2; ++i) {
                int idx = i * 256 + tid;
                int row = idx >> 3, cb = (idx & 7) * 8;
                *(bf16x8*)&wsh[w][row][cb] = wr[w][i];
            }
        __syncthreads();                 // tile visible

        if (kt < 15) {                   // prefetch next K-step
            const int kofs = (kt + 1) * 64;
#pragma unroll
            for (int i = 0; i < 4; ++i) {
                int idx = i * 256 + tid;
                int row = idx >> 3, cb = (idx & 7) * 8;
                xr[i] = *(const bf16x8*)&x[(size_t)(m0 + row) * DMODEL + kofs + cb];
            }
#pragma unroll
            for (int w = 0; w < 3; ++w)
#pragma unroll
                for (int i = 0; i < 2; ++i) {
                    int idx = i * 256 + tid;
                    int row = idx >> 3, cb = (idx & 7) * 8;
                    wr[w][i] = *(const bf16x8*)&wbase[w][(size_t)row * DMODEL + kofs + cb];
                }
        }

        bf16x8 af[2][2];
#pragma unroll
        for (int mi = 0; mi < 2; ++mi)
#pragma unroll
            for (int ks = 0; ks < 2; ++ks)
                af[mi][ks] = *(const bf16x8*)&xs[wid * 32 + mi * 16 + lr][ks * 32 + lg * 8];

#pragma unroll
        for (int w = 0; w < 3; ++w)
#pragma unroll
            for (int nt = 0; nt < 4; ++nt)
#pragma unroll
                for (int ks = 0; ks < 2; ++ks) {
                    bf16x8 bfr = *(const bf16x8*)&wsh[w][nt * 16 + lr][ks * 32 + lg * 8];
#pragma unroll
                    for (int mi = 0; mi < 2; ++mi)
                        acc[w][mi][nt] = mfma16(af[mi][ks], bfr, acc[w][mi][nt]);
                }
    }

    const float* bias[3] = { bq + h * DHEAD, bk + h * DHEAD, bv + h * DHEAD };
#pragma unroll
    for (int w = 0; w < 3; ++w)
#pragma unroll
        for (int nt = 0; nt < 4; ++nt) {
            int d = nt * 16 + lr;
            float bs = bias[w][d];
#pragma unroll
            for (int mi = 0; mi < 2; ++mi)
#pragma unroll
                for (int j = 0; j < 4; ++j) {
                    int mrow = m0 + wid * 32 + mi * 16 + lg * 4 + j;
                    int b = mrow >> 11, t = mrow & 2047;
                    float val = acc[w][mi][nt][j] + bs;
                    size_t bh = (size_t)b * NHEAD + h;
                    if (w == 0)
                        qws[(bh * T_SEQ + t) * DHEAD + d] = (bf16)val;
                    else if (w == 1)
                        kws[(bh * T_SEQ + t) * DHEAD + d] = (bf16)val;
                    else
                        vtws[(bh * DHEAD + d) * T_SEQ + t] = (bf16)val;
                }
        }
}

// ---------------------------------------------------------------------------
// Fused flash attention (unchanged from round 6).
// ---------------------------------------------------------------------------
__global__ __launch_bounds__(512) void attn_fused(
    const bf16* __restrict__ qws, const bf16* __restrict__ kws,
    const bf16* __restrict__ vtws, bf16* __restrict__ aws)
{
    __shared__ __align__(16) bf16 kls[2][64][72];
    __shared__ __align__(16) bf16 vls[2][64][72];
    __shared__ __align__(16) bf16 pls[128][72];

    const int qt = blockIdx.x;
    const int bh = blockIdx.y;
    const int b = bh >> 4, h = bh & 15;
    const bf16* Q  = qws  + (size_t)bh * T_SEQ * DHEAD;
    const bf16* K  = kws  + (size_t)bh * T_SEQ * DHEAD;
    const bf16* Vt = vtws + (size_t)bh * DHEAD * T_SEQ;

    const int tid = threadIdx.x, wid = tid >> 6, lane = tid & 63;
    const int lr = lane & 15, lg = lane >> 4;
    const int q0 = qt * 128 + wid * 16;

    const int srow = tid >> 3, scb = (tid & 7) * 8;

    bf16x8 qf[2];
#pragma unroll
    for (int ks = 0; ks < 2; ++ks) {
        bf16x8 v = *(const bf16x8*)&Q[(size_t)(q0 + lr) * DHEAD + ks * 32 + lg * 8];
#pragma unroll
        for (int j = 0; j < 8; ++j) v[j] = (bf16)((float)v[j] * 0.03125f);
        qf[ks] = v;
    }

    f32x4 o[4];
#pragma unroll
    for (int nt = 0; nt < 4; ++nt) o[nt] = (f32x4)0.0f;
    float mrun = -1e30f, lrun = 0.f;

    bf16x8 kr, vr;
    kr = *(const bf16x8*)&K[(size_t)srow * DHEAD + scb];
    vr = *(const bf16x8*)&Vt[(size_t)srow * T_SEQ + scb];
    *(bf16x8*)&kls[0][srow][scb] = kr;
    *(bf16x8*)&vls[0][srow][scb] = vr;

    int cur = 0;
    for (int t = 0; t < T_SEQ / 64; ++t) {
        __syncthreads();

        const bool more = (t + 1) < T_SEQ / 64;
        if (more) {
            int kvn = (t + 1) * 64;
            kr = *(const bf16x8*)&K[(size_t)(kvn + srow) * DHEAD + scb];
            vr = *(const bf16x8*)&Vt[(size_t)srow * T_SEQ + kvn + scb];
        }

        f32x4 s[4];
#pragma unroll
        for (int nt = 0; nt < 4; ++nt) {
            bf16x8 k0 = *(const bf16x8*)&kls[cur][nt * 16 + lr][0 + lg * 8];
            bf16x8 k1 = *(const bf16x8*)&kls[cur][nt * 16 + lr][32 + lg * 8];
            s[nt] = mfma16(k0, qf[0], (f32x4)0.0f);
            s[nt] = mfma16(k1, qf[1], s[nt]);
        }

        float vm0 = fmaxf(fmaxf(s[0][0], s[0][1]), fmaxf(s[0][2], s[0][3]));
        float vm1 = fmaxf(fmaxf(s[1][0], s[1][1]), fmaxf(s[1][2], s[1][3]));
        float vm2 = fmaxf(fmaxf(s[2][0], s[2][1]), fmaxf(s[2][2], s[2][3]));
        float vm3 = fmaxf(fmaxf(s[3][0], s[3][1]), fmaxf(s[3][2], s[3][3]));
        float vm = fmaxf(fmaxf(vm0, vm1), fmaxf(vm2, vm3));
        vm = fmaxf(vm, __shfl_xor(vm, 16));
        vm = fmaxf(vm, __shfl_xor(vm, 32));

        const bool skip = __all(vm <= mrun + 8.0f);
        float mnew = skip ? mrun : fmaxf(mrun, vm);
        float m2 = mnew * L2E;

        float p[4][4];
        float rs = 0.f;
#pragma unroll
        for (int nt = 0; nt < 4; ++nt)
#pragma unroll
            for (int j = 0; j < 4; ++j) {
                p[nt][j] = __builtin_amdgcn_exp2f(fmaf(s[nt][j], L2E, -m2));
                rs += p[nt][j];
            }
        rs += __shfl_xor(rs, 16);
        rs += __shfl_xor(rs, 32);

        if (skip) {
            lrun += rs;
        } else {
            float alpha = __builtin_amdgcn_exp2f((mrun - mnew) * L2E);
            lrun = lrun * alpha + rs;
            mrun = mnew;
            float ab[4];
#pragma unroll
            for (int j = 0; j < 4; ++j) ab[j] = __shfl(alpha, lg * 4 + j);
#pragma unroll
            for (int nt = 0; nt < 4; ++nt)
#pragma unroll
                for (int j = 0; j < 4; ++j) o[nt][j] *= ab[j];
        }

#pragma unroll
        for (int nt = 0; nt < 4; ++nt) {
            bf16x4 pk;
            pk[0] = (bf16)p[nt][0]; pk[1] = (bf16)p[nt][1];
            pk[2] = (bf16)p[nt][2]; pk[3] = (bf16)p[nt][3];
            *(bf16x4*)&pls[wid * 16 + lr][nt * 16 + 4 * lg] = pk;
        }

        asm volatile("s_waitcnt lgkmcnt(0)" ::: "memory");

#pragma unroll
        for (int ks = 0; ks < 2; ++ks) {
            bf16x8 pf = *(const bf16x8*)&pls[wid * 16 + lr][ks * 32 + lg * 8];
#pragma unroll
            for (int nt = 0; nt < 4; ++nt) {
                bf16x8 vf = *(const bf16x8*)&vls[cur][nt * 16 + lr][ks * 32 + lg * 8];
                o[nt] = mfma16(pf, vf, o[nt]);
            }
        }

        if (more) {
            *(bf16x8*)&kls[cur ^ 1][srow][scb] = kr;
            *(bf16x8*)&vls[cur ^ 1][srow][scb] = vr;
        }
        cur ^= 1;
    }

    float linv[4];
#pragma unroll
    for (int j = 0; j < 4; ++j) linv[j] = 1.0f / __shfl(lrun, lg * 4 + j);

    const size_t obase = ((size_t)b * T_SEQ) * DMODEL + (size_t)h * DHEAD;
#pragma unroll
    for (int nt = 0; nt < 4; ++nt) {
        int d = nt * 16 + lr;
#pragma unroll
        for (int j = 0; j < 4; ++j) {
            int t = q0 + lg * 4 + j;
            aws[obase + (size_t)t * DMODEL + d] = (bf16)(o[nt][j] * linv[j]);
        }
    }
}

// ---------------------------------------------------------------------------
// Output projection: 128x128 tiles + T14 register-prefetch pipeline.
// ---------------------------------------------------------------------------
__global__ __launch_bounds__(256) void out_gemm(
    const bf16* __restrict__ a, const bf16* __restrict__ wot,
    const float* __restrict__ bo, float* __restrict__ out)
{
    __shared__ __align__(16) bf16 as[128][72];
    __shared__ __align__(16) bf16 wsh[128][72];

    const int m0 = blockIdx.x * 128, n0 = blockIdx.y * 128;
    const int tid = threadIdx.x, wid = tid >> 6, lane = tid & 63;
    const int lr = lane & 15, lg = lane >> 4;

    f32x4 acc[2][8];
#pragma unroll
    for (int mi = 0; mi < 2; ++mi)
#pragma unroll
        for (int nt = 0; nt < 8; ++nt) acc[mi][nt] = (f32x4)0.0f;

    bf16x8 ar[4], wr[4];
#pragma unroll
    for (int i = 0; i < 4; ++i) {
        int idx = i * 256 + tid;
        int row = idx >> 3, cb = (idx & 7) * 8;
        ar[i] = *(const bf16x8*)&a[(size_t)(m0 + row) * DMODEL + cb];
        wr[i] = *(const bf16x8*)&wot[(size_t)(n0 + row) * DMODEL + cb];
    }

    for (int kt = 0; kt < 16; ++kt) {
        __syncthreads();
#pragma unroll
        for (int i = 0; i < 4; ++i) {
            int idx = i * 256 + tid;
            int row = idx >> 3, cb = (idx & 7) * 8;
            *(bf16x8*)&as[row][cb]  = ar[i];
            *(bf16x8*)&wsh[row][cb] = wr[i];
        }
        __syncthreads();

        if (kt < 15) {
            const int kofs = (kt + 1) * 64;
#pragma unroll
            for (int i = 0; i < 4; ++i) {
                int idx = i * 256 + tid;
                int row = idx >> 3, cb = (idx & 7) * 8;
                ar[i] = *(const bf16x8*)&a[(size_t)(m0 + row) * DMODEL + kofs + cb];
                wr[i] = *(const bf16x8*)&wot[(size_t)(n0 + row) * DMODEL + kofs + cb];
            }
        }

        bf16x8 af[2][2];
#pragma unroll
        for (int mi = 0; mi < 2; ++mi)
#pragma unroll
            for (int ks = 0; ks < 2; ++ks)
                af[mi][ks] = *(const bf16x8*)&as[wid * 32 + mi * 16 + lr][ks * 32 + lg * 8];

#pragma unroll
        for (int nt = 0; nt < 8; ++nt)
#pragma unroll
            for (int ks = 0; ks < 2; ++ks) {
                bf16x8 bfr = *(const bf16x8*)&wsh[nt * 16 + lr][ks * 32 + lg * 8];
#pragma unroll
                for (int mi = 0; mi < 2; ++mi)
                    acc[mi][nt] = mfma16(af[mi][ks], bfr, acc[mi][nt]);
            }
    }

#pragma unroll
    for (int nt = 0; nt < 8; ++nt) {
        int n = n0 + nt * 16 + lr;
        float bs = bo[n];
#pragma unroll
        for (int mi = 0; mi < 2; ++mi)
#pragma unroll
            for (int j = 0; j < 4; ++j) {
                int m = m0 + wid * 32 + mi * 16 + lg * 4 + j;
                out[(size_t)m * DMODEL + n] = acc[mi][nt][j] + bs;
            }
    }
}

// ---------------------------------------------------------------------------
extern "C" void kernel_launch(void* const* d_in, const int* in_sizes, int n_in,
                              void* d_out, int out_size, void* d_ws, size_t ws_size,
                              hipStream_t stream)
{
    const float* x  = (const float*)d_in[0];
    const float* Wq = (const float*)d_in[1];
    const float* Wk = (const float*)d_in[2];
    const float* Wv = (const float*)d_in[3];
    const float* bq = (const float*)d_in[4];
    const float* bk = (const float*)d_in[5];
    const float* bv = (const float*)d_in[6];
    const float* Wo = (const float*)d_in[7];
    const float* bo = (const float*)d_in[8];
    float* out = (float*)d_out;

    const size_t M1 = (size_t)1024 * 1024;
    bf16* ws   = (bf16*)d_ws;
    bf16* xbf  = ws;                 // 4M elems [4096][1024]; reused as aws later
    bf16* qws  = ws + 4 * M1;        // 4M  [b,h,t,d]
    bf16* kws  = qws + 4 * M1;       // 4M  [b,h,t,d]
    bf16* vtws = kws + 4 * M1;       // 4M  [b,h,d,t]
    bf16* wt   = vtws + 4 * M1;      // 3M  [3*h][d][c]
    bf16* wot  = wt + 3 * M1;        // 1M  [n][k]
    bf16* aws  = xbf;                // alias: x dead after qkv_gemm
    // total: 20M bf16 = 40 MB

    dim3 tb(256);
    prep<<<dim3(3072), tb, 0, stream>>>(x, xbf, Wq, Wk, Wv, wt, Wo, wot);
    qkv_gemm<<<dim3(MTOT / 128, NHEAD), tb, 0, stream>>>(xbf, wt, bq, bk, bv, qws, kws, vtws);
    attn_fused<<<dim3(T_SEQ / 128, 2 * NHEAD), dim3(512), 0, stream>>>(qws, kws, vtws, aws);
    out_gemm<<<dim3(MTOT / 128, DMODEL / 128), tb, 0, stream>>>(aws, wot, bo, out);
}

// Round 8
// 128.003 us; speedup vs baseline: 1.6628x; 1.0054x over previous
//
#include <hip/hip_runtime.h>

typedef __bf16 bf16;
typedef __bf16 bf16x4 __attribute__((ext_vector_type(4)));
typedef __bf16 bf16x8 __attribute__((ext_vector_type(8)));
typedef float  f32x4  __attribute__((ext_vector_type(4)));

#define T_SEQ  2048
#define NHEAD  16
#define DHEAD  64
#define DMODEL 1024
#define MTOT   4096  // B*T
#define L2E    1.4426950408889634f

static __device__ __forceinline__ f32x4 mfma16(bf16x8 a, bf16x8 b, f32x4 c) {
    return __builtin_amdgcn_mfma_f32_16x16x32_bf16(a, b, c, 0, 0, 0);
}

// ---------------------------------------------------------------------------
// prep: one kernel for all preprocessing.
//   blocks [0, 2048)        : x fp32 -> bf16 convert (8 elems/thread)
//   blocks [2048, 2816)     : Wq/Wk/Wv transpose  [1024,64] -> [64,1024] bf16
//   blocks [2816, 3072)     : Wo transpose        [1024,1024] -> [1024,1024]^T
// ---------------------------------------------------------------------------
__global__ __launch_bounds__(256) void prep(
    const float* __restrict__ x,  bf16* __restrict__ xbf,
    const float* __restrict__ Wq, const float* __restrict__ Wk,
    const float* __restrict__ Wv, bf16* __restrict__ wt,
    const float* __restrict__ Wo, bf16* __restrict__ wot)
{
    __shared__ float t[64][68];
    const int bid = blockIdx.x, tid = threadIdx.x;

    if (bid < 2048) {                 // ---- convert x ----
        const int i = bid * 256 + tid;
        const float4 a = ((const float4*)x)[i * 2];
        const float4 b = ((const float4*)x)[i * 2 + 1];
        bf16x8 v;
        v[0] = (bf16)a.x; v[1] = (bf16)a.y; v[2] = (bf16)a.z; v[3] = (bf16)a.w;
        v[4] = (bf16)b.x; v[5] = (bf16)b.y; v[6] = (bf16)b.z; v[7] = (bf16)b.w;
        ((bf16x8*)xbf)[i] = v;
        return;
    }

    // ---- transposes ----
    const float* in; bf16* out;
    int R, Cc; long ib, ob; int r0, c0;
    if (bid < 2816) {
        int b2 = bid - 2048;
        int w = b2 >> 8, rem = b2 & 255;          // w in 0..2, rem in 0..255
        int rt = rem & 15, head = rem >> 4;
        in  = (w == 0 ? Wq : w == 1 ? Wk : Wv);
        out = wt + (size_t)w * 1024 * 1024;
        R = 1024; Cc = 64;
        ib = (long)head * 65536; ob = (long)head * 65536;
        r0 = rt * 64; c0 = 0;
    } else {
        int b3 = bid - 2816;
        in = Wo; out = wot;
        R = 1024; Cc = 1024;
        ib = 0; ob = 0;
        r0 = (b3 & 15) * 64; c0 = (b3 >> 4) * 64;
    }

#pragma unroll
    for (int i = 0; i < 4; ++i) {                 // load 64x64 fp32 tile
        int idx = i * 256 + tid;
        int row = idx >> 4, cb = (idx & 15) * 4;
        float4 v = *(const float4*)&in[ib + (long)(r0 + row) * Cc + c0 + cb];
        t[row][cb + 0] = v.x; t[row][cb + 1] = v.y;
        t[row][cb + 2] = v.z; t[row][cb + 3] = v.w;
    }
    __syncthreads();
#pragma unroll
    for (int i = 0; i < 2; ++i) {                 // store 64x64 bf16 transposed
        int idx = i * 256 + tid;
        int row = idx >> 3, cb = (idx & 7) * 8;   // row = out-row (col of in)
        bf16x8 v;
#pragma unroll
        for (int j = 0; j < 8; ++j) v[j] = (bf16)t[cb + j][row];
        *(bf16x8*)&out[ob + (long)(c0 + row) * R + r0 + cb] = v;
    }
}

// ---------------------------------------------------------------------------
// QKV projection with T14 register-prefetch pipeline.
// ---------------------------------------------------------------------------
__global__ __launch_bounds__(256) void qkv_gemm(
    const bf16* __restrict__ x, const bf16* __restrict__ wt,
    const float* __restrict__ bq, const float* __restrict__ bk,
    const float* __restrict__ bv,
    bf16* __restrict__ qws, bf16* __restrict__ kws, bf16* __restrict__ vtws)
{
    __shared__ __align__(16) bf16 xs[128][72];
    __shared__ __align__(16) bf16 wsh[3][64][72];

    const int m0 = blockIdx.x * 128;
    const int h  = blockIdx.y;
    const int tid = threadIdx.x, wid = tid >> 6, lane = tid & 63;
    const int lr = lane & 15, lg = lane >> 4;

    const bf16* wbase[3];
#pragma unroll
    for (int w = 0; w < 3; ++w)
        wbase[w] = wt + ((size_t)(w * NHEAD + h)) * DHEAD * DMODEL;

    f32x4 acc[3][2][4];
#pragma unroll
    for (int w = 0; w < 3; ++w)
#pragma unroll
        for (int mi = 0; mi < 2; ++mi)
#pragma unroll
            for (int nt = 0; nt < 4; ++nt) acc[w][mi][nt] = (f32x4)0.0f;

    bf16x8 xr[4], wr[3][2];
#pragma unroll
    for (int i = 0; i < 4; ++i) {
        int idx = i * 256 + tid;
        int row = idx >> 3, cb = (idx & 7) * 8;
        xr[i] = *(const bf16x8*)&x[(size_t)(m0 + row) * DMODEL + cb];
    }
#pragma unroll
    for (int w = 0; w < 3; ++w)
#pragma unroll
        for (int i = 0; i < 2; ++i) {
            int idx = i * 256 + tid;
            int row = idx >> 3, cb = (idx & 7) * 8;
            wr[w][i] = *(const bf16x8*)&wbase[w][(size_t)row * DMODEL + cb];
        }

    for (int kt = 0; kt < 16; ++kt) {
        __syncthreads();                 // previous compute done reading LDS
#pragma unroll
        for (int i = 0; i < 4; ++i) {
            int idx = i * 256 + tid;
            int row = idx >> 3, cb = (idx & 7) * 8;
            *(bf16x8*)&xs[row][cb] = xr[i];
        }
#pragma unroll
        for (int w = 0; w < 3; ++w)
#pragma unroll
            for (int i = 0; i < 2; ++i) {
                int idx = i * 256 + tid;
                int row = idx >> 3, cb = (idx & 7) * 8;
                *(bf16x8*)&wsh[w][row][cb] = wr[w][i];
            }
        __syncthreads();                 // tile visible

        if (kt < 15) {                   // prefetch next K-step
            const int kofs = (kt + 1) * 64;
#pragma unroll
            for (int i = 0; i < 4; ++i) {
                int idx = i * 256 + tid;
                int row = idx >> 3, cb = (idx & 7) * 8;
                xr[i] = *(const bf16x8*)&x[(size_t)(m0 + row) * DMODEL + kofs + cb];
            }
#pragma unroll
            for (int w = 0; w < 3; ++w)
#pragma unroll
                for (int i = 0; i < 2; ++i) {
                    int idx = i * 256 + tid;
                    int row = idx >> 3, cb = (idx & 7) * 8;
                    wr[w][i] = *(const bf16x8*)&wbase[w][(size_t)row * DMODEL + kofs + cb];
                }
        }

        bf16x8 af[2][2];
#pragma unroll
        for (int mi = 0; mi < 2; ++mi)
#pragma unroll
            for (int ks = 0; ks < 2; ++ks)
                af[mi][ks] = *(const bf16x8*)&xs[wid * 32 + mi * 16 + lr][ks * 32 + lg * 8];

#pragma unroll
        for (int w = 0; w < 3; ++w)
#pragma unroll
            for (int nt = 0; nt < 4; ++nt)
#pragma unroll
                for (int ks = 0; ks < 2; ++ks) {
                    bf16x8 bfr = *(const bf16x8*)&wsh[w][nt * 16 + lr][ks * 32 + lg * 8];
#pragma unroll
                    for (int mi = 0; mi < 2; ++mi)
                        acc[w][mi][nt] = mfma16(af[mi][ks], bfr, acc[w][mi][nt]);
                }
    }

    const float* bias[3] = { bq + h * DHEAD, bk + h * DHEAD, bv + h * DHEAD };
#pragma unroll
    for (int w = 0; w < 3; ++w)
#pragma unroll
        for (int nt = 0; nt < 4; ++nt) {
            int d = nt * 16 + lr;
            float bs = bias[w][d];
#pragma unroll
            for (int mi = 0; mi < 2; ++mi)
#pragma unroll
                for (int j = 0; j < 4; ++j) {
                    int mrow = m0 + wid * 32 + mi * 16 + lg * 4 + j;
                    int b = mrow >> 11, t = mrow & 2047;
                    float val = acc[w][mi][nt][j] + bs;
                    size_t bh = (size_t)b * NHEAD + h;
                    if (w == 0)
                        qws[(bh * T_SEQ + t) * DHEAD + d] = (bf16)val;
                    else if (w == 1)
                        kws[(bh * T_SEQ + t) * DHEAD + d] = (bf16)val;
                    else
                        vtws[(bh * DHEAD + d) * T_SEQ + t] = (bf16)val;
                }
        }
}

// ---------------------------------------------------------------------------
// Fused flash attention.
// Round-8 changes: pls stride 68 (-2.3KB -> 53.0KB total, 3 blocks/CU),
// P-read as 2x ds_read_b64; s_setprio around MFMA clusters; XCD-aware
// block swizzle (each XCD owns 4 consecutive bh -> KV set fits its L2).
// ---------------------------------------------------------------------------
__global__ __launch_bounds__(512) void attn_fused(
    const bf16* __restrict__ qws, const bf16* __restrict__ kws,
    const bf16* __restrict__ vtws, bf16* __restrict__ aws)
{
    __shared__ __align__(16) bf16 kls[2][64][72];
    __shared__ __align__(16) bf16 vls[2][64][72];
    __shared__ __align__(16) bf16 pls[128][68];

    // XCD swizzle: 512 blocks, XCD = id%8 (round-robin). Give XCD r the
    // contiguous work range [64r, 64r+64) = 4 consecutive bh values.
    const int id = blockIdx.x;
    const int w  = (id & 7) * 64 + (id >> 3);
    const int qt = w & 15;
    const int bh = w >> 4;

    const int b = bh >> 4, h = bh & 15;
    const bf16* Q  = qws  + (size_t)bh * T_SEQ * DHEAD;
    const bf16* K  = kws  + (size_t)bh * T_SEQ * DHEAD;
    const bf16* Vt = vtws + (size_t)bh * DHEAD * T_SEQ;

    const int tid = threadIdx.x, wid = tid >> 6, lane = tid & 63;
    const int lr = lane & 15, lg = lane >> 4;
    const int q0 = qt * 128 + wid * 16;

    const int srow = tid >> 3, scb = (tid & 7) * 8;

    bf16x8 qf[2];
#pragma unroll
    for (int ks = 0; ks < 2; ++ks) {
        bf16x8 v = *(const bf16x8*)&Q[(size_t)(q0 + lr) * DHEAD + ks * 32 + lg * 8];
#pragma unroll
        for (int j = 0; j < 8; ++j) v[j] = (bf16)((float)v[j] * 0.03125f);
        qf[ks] = v;
    }

    f32x4 o[4];
#pragma unroll
    for (int nt = 0; nt < 4; ++nt) o[nt] = (f32x4)0.0f;
    float mrun = -1e30f, lrun = 0.f;

    bf16x8 kr, vr;
    kr = *(const bf16x8*)&K[(size_t)srow * DHEAD + scb];
    vr = *(const bf16x8*)&Vt[(size_t)srow * T_SEQ + scb];
    *(bf16x8*)&kls[0][srow][scb] = kr;
    *(bf16x8*)&vls[0][srow][scb] = vr;

    int cur = 0;
    for (int t = 0; t < T_SEQ / 64; ++t) {
        __syncthreads();

        const bool more = (t + 1) < T_SEQ / 64;
        if (more) {
            int kvn = (t + 1) * 64;
            kr = *(const bf16x8*)&K[(size_t)(kvn + srow) * DHEAD + scb];
            vr = *(const bf16x8*)&Vt[(size_t)srow * T_SEQ + kvn + scb];
        }

        f32x4 s[4];
        __builtin_amdgcn_s_setprio(1);
#pragma unroll
        for (int nt = 0; nt < 4; ++nt) {
            bf16x8 k0 = *(const bf16x8*)&kls[cur][nt * 16 + lr][0 + lg * 8];
            bf16x8 k1 = *(const bf16x8*)&kls[cur][nt * 16 + lr][32 + lg * 8];
            s[nt] = mfma16(k0, qf[0], (f32x4)0.0f);
            s[nt] = mfma16(k1, qf[1], s[nt]);
        }
        __builtin_amdgcn_s_setprio(0);

        float vm0 = fmaxf(fmaxf(s[0][0], s[0][1]), fmaxf(s[0][2], s[0][3]));
        float vm1 = fmaxf(fmaxf(s[1][0], s[1][1]), fmaxf(s[1][2], s[1][3]));
        float vm2 = fmaxf(fmaxf(s[2][0], s[2][1]), fmaxf(s[2][2], s[2][3]));
        float vm3 = fmaxf(fmaxf(s[3][0], s[3][1]), fmaxf(s[3][2], s[3][3]));
        float vm = fmaxf(fmaxf(vm0, vm1), fmaxf(vm2, vm3));
        vm = fmaxf(vm, __shfl_xor(vm, 16));
        vm = fmaxf(vm, __shfl_xor(vm, 32));

        const bool skip = __all(vm <= mrun + 8.0f);
        float mnew = skip ? mrun : fmaxf(mrun, vm);
        float m2 = mnew * L2E;

        float p[4][4];
        float rs = 0.f;
#pragma unroll
        for (int nt = 0; nt < 4; ++nt)
#pragma unroll
            for (int j = 0; j < 4; ++j) {
                p[nt][j] = __builtin_amdgcn_exp2f(fmaf(s[nt][j], L2E, -m2));
                rs += p[nt][j];
            }
        rs += __shfl_xor(rs, 16);
        rs += __shfl_xor(rs, 32);

        if (skip) {
            lrun += rs;
        } else {
            float alpha = __builtin_amdgcn_exp2f((mrun - mnew) * L2E);
            lrun = lrun * alpha + rs;
            mrun = mnew;
            float ab[4];
#pragma unroll
            for (int j = 0; j < 4; ++j) ab[j] = __shfl(alpha, lg * 4 + j);
#pragma unroll
            for (int nt = 0; nt < 4; ++nt)
#pragma unroll
                for (int j = 0; j < 4; ++j) o[nt][j] *= ab[j];
        }

#pragma unroll
        for (int nt = 0; nt < 4; ++nt) {
            bf16x4 pk;
            pk[0] = (bf16)p[nt][0]; pk[1] = (bf16)p[nt][1];
            pk[2] = (bf16)p[nt][2]; pk[3] = (bf16)p[nt][3];
            *(bf16x4*)&pls[wid * 16 + lr][nt * 16 + 4 * lg] = pk;
        }

        asm volatile("s_waitcnt lgkmcnt(0)" ::: "memory");

        __builtin_amdgcn_s_setprio(1);
#pragma unroll
        for (int ks = 0; ks < 2; ++ks) {
            bf16x4 ph0 = *(const bf16x4*)&pls[wid * 16 + lr][ks * 32 + lg * 8];
            bf16x4 ph1 = *(const bf16x4*)&pls[wid * 16 + lr][ks * 32 + lg * 8 + 4];
            bf16x8 pf = __builtin_shufflevector(ph0, ph1, 0, 1, 2, 3, 4, 5, 6, 7);
#pragma unroll
            for (int nt = 0; nt < 4; ++nt) {
                bf16x8 vf = *(const bf16x8*)&vls[cur][nt * 16 + lr][ks * 32 + lg * 8];
                o[nt] = mfma16(pf, vf, o[nt]);
            }
        }
        __builtin_amdgcn_s_setprio(0);

        if (more) {
            *(bf16x8*)&kls[cur ^ 1][srow][scb] = kr;
            *(bf16x8*)&vls[cur ^ 1][srow][scb] = vr;
        }
        cur ^= 1;
    }

    float linv[4];
#pragma unroll
    for (int j = 0; j < 4; ++j) linv[j] = 1.0f / __shfl(lrun, lg * 4 + j);

    const size_t obase = ((size_t)b * T_SEQ) * DMODEL + (size_t)h * DHEAD;
#pragma unroll
    for (int nt = 0; nt < 4; ++nt) {
        int d = nt * 16 + lr;
#pragma unroll
        for (int j = 0; j < 4; ++j) {
            int t = q0 + lg * 4 + j;
            aws[obase + (size_t)t * DMODEL + d] = (bf16)(o[nt][j] * linv[j]);
        }
    }
}

// ---------------------------------------------------------------------------
// Output projection: 128x128 tiles + T14 register-prefetch pipeline.
// ---------------------------------------------------------------------------
__global__ __launch_bounds__(256) void out_gemm(
    const bf16* __restrict__ a, const bf16* __restrict__ wot,
    const float* __restrict__ bo, float* __restrict__ out)
{
    __shared__ __align__(16) bf16 as[128][72];
    __shared__ __align__(16) bf16 wsh[128][72];

    const int m0 = blockIdx.x * 128, n0 = blockIdx.y * 128;
    const int tid = threadIdx.x, wid = tid >> 6, lane = tid & 63;
    const int lr = lane & 15, lg = lane >> 4;

    f32x4 acc[2][8];
#pragma unroll
    for (int mi = 0; mi < 2; ++mi)
#pragma unroll
        for (int nt = 0; nt < 8; ++nt) acc[mi][nt] = (f32x4)0.0f;

    bf16x8 ar[4], wr[4];
#pragma unroll
    for (int i = 0; i < 4; ++i) {
        int idx = i * 256 + tid;
        int row = idx >> 3, cb = (idx & 7) * 8;
        ar[i] = *(const bf16x8*)&a[(size_t)(m0 + row) * DMODEL + cb];
        wr[i] = *(const bf16x8*)&wot[(size_t)(n0 + row) * DMODEL + cb];
    }

    for (int kt = 0; kt < 16; ++kt) {
        __syncthreads();
#pragma unroll
        for (int i = 0; i < 4; ++i) {
            int idx = i * 256 + tid;
            int row = idx >> 3, cb = (idx & 7) * 8;
            *(bf16x8*)&as[row][cb]  = ar[i];
            *(bf16x8*)&wsh[row][cb] = wr[i];
        }
        __syncthreads();

        if (kt < 15) {
            const int kofs = (kt + 1) * 64;
#pragma unroll
            for (int i = 0; i < 4; ++i) {
                int idx = i * 256 + tid;
                int row = idx >> 3, cb = (idx & 7) * 8;
                ar[i] = *(const bf16x8*)&a[(size_t)(m0 + row) * DMODEL + kofs + cb];
                wr[i] = *(const bf16x8*)&wot[(size_t)(n0 + row) * DMODEL + kofs + cb];
            }
        }

        bf16x8 af[2][2];
#pragma unroll
        for (int mi = 0; mi < 2; ++mi)
#pragma unroll
            for (int ks = 0; ks < 2; ++ks)
                af[mi][ks] = *(const bf16x8*)&as[wid * 32 + mi * 16 + lr][ks * 32 + lg * 8];

#pragma unroll
        for (int nt = 0; nt < 8; ++nt)
#pragma unroll
            for (int ks = 0; ks < 2; ++ks) {
                bf16x8 bfr = *(const bf16x8*)&wsh[nt * 16 + lr][ks * 32 + lg * 8];
#pragma unroll
                for (int mi = 0; mi < 2; ++mi)
                    acc[mi][nt] = mfma16(af[mi][ks], bfr, acc[mi][nt]);
            }
    }

#pragma unroll
    for (int nt = 0; nt < 8; ++nt) {
        int n = n0 + nt * 16 + lr;
        float bs = bo[n];
#pragma unroll
        for (int mi = 0; mi < 2; ++mi)
#pragma unroll
            for (int j = 0; j < 4; ++j) {
                int m = m0 + wid * 32 + mi * 16 + lg * 4 + j;
                out[(size_t)m * DMODEL + n] = acc[mi][nt][j] + bs;
            }
    }
}

// ---------------------------------------------------------------------------
extern "C" void kernel_launch(void* const* d_in, const int* in_sizes, int n_in,
                              void* d_out, int out_size, void* d_ws, size_t ws_size,
                              hipStream_t stream)
{
    const float* x  = (const float*)d_in[0];
    const float* Wq = (const float*)d_in[1];
    const float* Wk = (const float*)d_in[2];
    const float* Wv = (const float*)d_in[3];
    const float* bq = (const float*)d_in[4];
    const float* bk = (const float*)d_in[5];
    const float* bv = (const float*)d_in[6];
    const float* Wo = (const float*)d_in[7];
    const float* bo = (const float*)d_in[8];
    float* out = (float*)d_out;

    const size_t M1 = (size_t)1024 * 1024;
    bf16* ws   = (bf16*)d_ws;
    bf16* xbf  = ws;                 // 4M elems [4096][1024]; reused as aws later
    bf16* qws  = ws + 4 * M1;        // 4M  [b,h,t,d]
    bf16* kws  = qws + 4 * M1;       // 4M  [b,h,t,d]
    bf16* vtws = kws + 4 * M1;       // 4M  [b,h,d,t]
    bf16* wt   = vtws + 4 * M1;      // 3M  [3*h][d][c]
    bf16* wot  = wt + 3 * M1;        // 1M  [n][k]
    bf16* aws  = xbf;                // alias: x dead after qkv_gemm
    // total: 20M bf16 = 40 MB

    dim3 tb(256);
    prep<<<dim3(3072), tb, 0, stream>>>(x, xbf, Wq, Wk, Wv, wt, Wo, wot);
    qkv_gemm<<<dim3(MTOT / 128, NHEAD), tb, 0, stream>>>(xbf, wt, bq, bk, bv, qws, kws, vtws);
    attn_fused<<<dim3(512), dim3(512), 0, stream>>>(qws, kws, vtws, aws);
    out_gemm<<<dim3(MTOT / 128, DMODEL / 128), tb, 0, stream>>>(aws, wot, bo, out);
}